// Round 1
// baseline (8604.632 us; speedup 1.0000x reference)
//
#include <hip/hip_runtime.h>

#define N_NODES  100000
#define N_EDGES  1600000
#define N_GRAPHS 512
#define D_H      128
#define N_LAYERS 3

// ---------------------------------------------------------------------------
// Fused GEMM: out = relu( (A1 .* S1[row]) @ B1 + [A2 @ B2] + bias )
// A: [M][128] row-major, B: [128][128] row-major, out: [M][128]
// Tile: 128 rows x 128 cols per block, 256 threads, 8x8 micro-tile.
// ---------------------------------------------------------------------------
#define KC 32
#define MT 128

__global__ __launch_bounds__(256) void gemm_fused(
    const float* __restrict__ A1, const float* __restrict__ S1,
    const float* __restrict__ B1,
    const float* __restrict__ A2, const float* __restrict__ B2,
    const float* __restrict__ bias, float* __restrict__ out, int M)
{
    __shared__ float As[KC][MT + 4];   // transposed A tile, padded
    __shared__ float Bs[KC][D_H];

    const int t  = threadIdx.x;
    const int tx = t & 15;             // col group (8 cols)
    const int ty = t >> 4;             // row group (8 rows)
    const int row0 = blockIdx.x * MT;

    float acc[8][8];
#pragma unroll
    for (int i = 0; i < 8; i++)
#pragma unroll
        for (int j = 0; j < 8; j++) acc[i][j] = 0.f;

    const int nsrc = A2 ? 2 : 1;
    for (int s = 0; s < nsrc; s++) {
        const float* __restrict__ A = s ? A2 : A1;
        const float* __restrict__ B = s ? B2 : B1;
        const float* __restrict__ S = s ? nullptr : S1;
        for (int k0 = 0; k0 < D_H; k0 += KC) {
            __syncthreads();
            // A tile -> LDS (transposed). 128x32 floats, 4 passes of float4.
#pragma unroll
            for (int it = 0; it < 4; it++) {
                const int lr = (t >> 3) + it * 32;
                const int lk = (t & 7) * 4;
                const int r  = row0 + lr;
                float4 v = make_float4(0.f, 0.f, 0.f, 0.f);
                if (r < M) {
                    v = *(const float4*)&A[(size_t)r * D_H + k0 + lk];
                    if (S) { const float sc = S[r]; v.x *= sc; v.y *= sc; v.z *= sc; v.w *= sc; }
                }
                As[lk + 0][lr] = v.x; As[lk + 1][lr] = v.y;
                As[lk + 2][lr] = v.z; As[lk + 3][lr] = v.w;
            }
            // B tile -> LDS. 32x128 floats, 4 passes of float4.
#pragma unroll
            for (int it = 0; it < 4; it++) {
                const int kr = (t >> 5) + it * 8;
                const int c  = (t & 31) * 4;
                *(float4*)&Bs[kr][c] = *(const float4*)&B[(size_t)(k0 + kr) * D_H + c];
            }
            __syncthreads();
#pragma unroll 8
            for (int kk = 0; kk < KC; kk++) {
                const float4 a0 = *(const float4*)&As[kk][ty * 8];
                const float4 a1 = *(const float4*)&As[kk][ty * 8 + 4];
                const float4 b0 = *(const float4*)&Bs[kk][tx * 8];
                const float4 b1 = *(const float4*)&Bs[kk][tx * 8 + 4];
                const float a[8] = {a0.x, a0.y, a0.z, a0.w, a1.x, a1.y, a1.z, a1.w};
                const float b[8] = {b0.x, b0.y, b0.z, b0.w, b1.x, b1.y, b1.z, b1.w};
#pragma unroll
                for (int i = 0; i < 8; i++)
#pragma unroll
                    for (int j = 0; j < 8; j++) acc[i][j] += a[i] * b[j];
            }
        }
    }

    float bv[8];
#pragma unroll
    for (int j = 0; j < 8; j++) bv[j] = bias[tx * 8 + j];
#pragma unroll
    for (int i = 0; i < 8; i++) {
        const int r = row0 + ty * 8 + i;
        if (r < M) {
            float4 o0, o1;
            o0.x = fmaxf(acc[i][0] + bv[0], 0.f);
            o0.y = fmaxf(acc[i][1] + bv[1], 0.f);
            o0.z = fmaxf(acc[i][2] + bv[2], 0.f);
            o0.w = fmaxf(acc[i][3] + bv[3], 0.f);
            o1.x = fmaxf(acc[i][4] + bv[4], 0.f);
            o1.y = fmaxf(acc[i][5] + bv[5], 0.f);
            o1.z = fmaxf(acc[i][6] + bv[6], 0.f);
            o1.w = fmaxf(acc[i][7] + bv[7], 0.f);
            *(float4*)&out[(size_t)r * D_H + tx * 8]     = o0;
            *(float4*)&out[(size_t)r * D_H + tx * 8 + 4] = o1;
        }
    }
}

// ---------------------------------------------------------------------------
// Edge scatter: agg[dst] += h[src]  (grid-stride over edge x feature-quads)
// ---------------------------------------------------------------------------
__global__ __launch_bounds__(256) void scatter_add(
    const float* __restrict__ h, const int* __restrict__ src,
    const int* __restrict__ dst, float* __restrict__ agg)
{
    const int total = N_EDGES * 32;          // 32 float4-groups per edge row
    const int stride = gridDim.x * blockDim.x;
    for (int i = blockIdx.x * blockDim.x + threadIdx.x; i < total; i += stride) {
        const int e = i >> 5;
        const int f = (i & 31) * 4;
        const int sN = src[e];
        const int dN = dst[e];
        const float4 v = *(const float4*)&h[(size_t)sN * D_H + f];
        float* p = &agg[(size_t)dN * D_H + f];
        atomicAdd(p + 0, v.x);
        atomicAdd(p + 1, v.y);
        atomicAdd(p + 2, v.z);
        atomicAdd(p + 3, v.w);
    }
}

__global__ __launch_bounds__(256) void deg_kernel(
    const int* __restrict__ dst, float* __restrict__ deg)
{
    const int e = blockIdx.x * blockDim.x + threadIdx.x;
    if (e < N_EDGES) atomicAdd(&deg[dst[e]], 1.0f);
}

__global__ __launch_bounds__(256) void inv_kernel(
    const float* __restrict__ deg, float* __restrict__ inv)
{
    const int n = blockIdx.x * blockDim.x + threadIdx.x;
    if (n < N_NODES) inv[n] = 1.0f / fmaxf(deg[n], 1.0f);
}

// graph node counts via binary search on sorted batch_idx
__global__ __launch_bounds__(256) void graph_cnt_kernel(
    const int* __restrict__ batch, float* __restrict__ cnt)
{
    const int g = blockIdx.x * blockDim.x + threadIdx.x;
    if (g >= N_GRAPHS) return;
    auto lb = [&](int v) {
        int lo = 0, hi = N_NODES;
        while (lo < hi) { const int m = (lo + hi) >> 1; if (batch[m] < v) lo = m + 1; else hi = m; }
        return lo;
    };
    cnt[g] = (float)(lb(g + 1) - lb(g));
}

// ---------------------------------------------------------------------------
// Pooling: per-thread run-length accumulate (batch_idx sorted), flush atomics
// on graph change. h >= 0 (post-relu) so int atomicMax works on float bits.
// ---------------------------------------------------------------------------
#define NPB 512
__global__ __launch_bounds__(256) void pool_kernel(
    const float* __restrict__ h, const int* __restrict__ batch,
    float* __restrict__ sumb, float* __restrict__ maxb)
{
    const int f   = threadIdx.x & 127;
    const int sub = threadIdx.x >> 7;
    const int n0  = blockIdx.x * NPB;
    const int nEnd = min(n0 + NPB, N_NODES);
    float sum = 0.f, mx = 0.f;
    int g = -1;
    for (int n = n0 + sub; n < nEnd; n += 2) {
        const int gb = batch[n];
        if (gb != g) {
            if (g >= 0) {
                atomicAdd(&sumb[g * D_H + f], sum);
                atomicMax((int*)&maxb[g * D_H + f], __float_as_int(mx));
            }
            g = gb; sum = 0.f; mx = 0.f;
        }
        const float v = h[(size_t)n * D_H + f];
        sum += v; mx = fmaxf(mx, v);
    }
    if (g >= 0) {
        atomicAdd(&sumb[g * D_H + f], sum);
        atomicMax((int*)&maxb[g * D_H + f], __float_as_int(mx));
    }
}

// ---------------------------------------------------------------------------
// Head MLP: z = [sum/cnt, max, gf]; out = relu(relu(z@W1+b1)@W2+b2)
// one block per graph, 128 threads
// ---------------------------------------------------------------------------
__global__ __launch_bounds__(128) void mlp_kernel(
    const float* __restrict__ sumb, const float* __restrict__ maxb,
    const float* __restrict__ cnt,  const float* __restrict__ gf,
    const float* __restrict__ W1, const float* __restrict__ b1,
    const float* __restrict__ W2, const float* __restrict__ b2,
    float* __restrict__ out)
{
    __shared__ float z[2 * D_H + 32];
    __shared__ float z1[D_H];
    const int g = blockIdx.x, t = threadIdx.x;
    const float ic = 1.0f / fmaxf(cnt[g], 1.0f);
    z[t]        = sumb[g * D_H + t] * ic;
    z[D_H + t]  = maxb[g * D_H + t];
    if (t < 32) z[2 * D_H + t] = gf[g * 32 + t];
    __syncthreads();
    float a = b1[t];
    for (int k = 0; k < 2 * D_H + 32; k++) a += z[k] * W1[k * D_H + t];
    a = fmaxf(a, 0.f);
    z1[t] = a;
    __syncthreads();
    float o = b2[t];
    for (int k = 0; k < D_H; k++) o += z1[k] * W2[k * D_H + t];
    out[g * D_H + t] = fmaxf(o, 0.f);
}

// ---------------------------------------------------------------------------
extern "C" void kernel_launch(void* const* d_in, const int* in_sizes, int n_in,
                              void* d_out, int out_size, void* d_ws, size_t ws_size,
                              hipStream_t stream)
{
    const float* x     = (const float*)d_in[0];
    const int*   ei    = (const int*)d_in[1];
    const int*   batch = (const int*)d_in[2];
    const float* gf    = (const float*)d_in[3];
    const float* W_in  = (const float*)d_in[4];
    const float* b_in  = (const float*)d_in[5];
    const float* Wl    = (const float*)d_in[6];
    const float* bl    = (const float*)d_in[7];
    const float* Wr    = (const float*)d_in[8];
    const float* W1    = (const float*)d_in[9];
    const float* b1    = (const float*)d_in[10];
    const float* W2    = (const float*)d_in[11];
    const float* b2    = (const float*)d_in[12];
    float* out = (float*)d_out;

    const int* srcI = ei;
    const int* dstI = ei + N_EDGES;

    // workspace layout (~155 MB)
    char* ws = (char*)d_ws;
    size_t off = 0;
    auto alloc = [&](size_t bytes) {
        char* p = ws + off;
        off += (bytes + 511) / 512 * 512;
        return p;
    };
    const size_t hBytes = (size_t)N_NODES * D_H * sizeof(float);
    float* h    = (float*)alloc(hBytes);
    float* hn   = (float*)alloc(hBytes);
    float* agg  = (float*)alloc(hBytes);
    float* deg  = (float*)alloc(N_NODES * sizeof(float));
    float* inv  = (float*)alloc(N_NODES * sizeof(float));
    float* sumb = (float*)alloc(N_GRAPHS * D_H * sizeof(float));
    float* maxb = (float*)alloc(N_GRAPHS * D_H * sizeof(float));
    float* cnt  = (float*)alloc(N_GRAPHS * sizeof(float));

    hipMemsetAsync(deg,  0, N_NODES * sizeof(float), stream);
    hipMemsetAsync(sumb, 0, N_GRAPHS * D_H * sizeof(float), stream);
    hipMemsetAsync(maxb, 0, N_GRAPHS * D_H * sizeof(float), stream);

    graph_cnt_kernel<<<(N_GRAPHS + 255) / 256, 256, 0, stream>>>(batch, cnt);
    deg_kernel<<<(N_EDGES + 255) / 256, 256, 0, stream>>>(dstI, deg);
    inv_kernel<<<(N_NODES + 255) / 256, 256, 0, stream>>>(deg, inv);

    const int gblocks = (N_NODES + MT - 1) / MT;
    gemm_fused<<<gblocks, 256, 0, stream>>>(x, nullptr, W_in, nullptr, nullptr, b_in, h, N_NODES);

    for (int l = 0; l < N_LAYERS; l++) {
        hipMemsetAsync(agg, 0, hBytes, stream);
        scatter_add<<<16384, 256, 0, stream>>>(h, srcI, dstI, agg);
        gemm_fused<<<gblocks, 256, 0, stream>>>(agg, inv, Wl + (size_t)l * D_H * D_H,
                                                h, Wr + (size_t)l * D_H * D_H,
                                                bl + (size_t)l * D_H, hn, N_NODES);
        float* tmp = h; h = hn; hn = tmp;
    }

    pool_kernel<<<(N_NODES + NPB - 1) / NPB, 256, 0, stream>>>(h, batch, sumb, maxb);
    mlp_kernel<<<N_GRAPHS, 128, 0, stream>>>(sumb, maxb, cnt, gf, W1, b1, W2, b2, out);
}

// Round 2
// 1023.274 us; speedup vs baseline: 8.4089x; 8.4089x over previous
//
#include <hip/hip_runtime.h>

#define N_NODES  100000
#define N_EDGES  1600000
#define N_GRAPHS 512
#define D_H      128
#define N_LAYERS 3

// ---------------------------------------------------------------------------
// Fused GEMM: out = relu( (A1 .* S1[row]) @ B1 + [A2 @ B2] + bias )
// NOTE: `out` may alias A1 — each block reads only its own A1 rows (all K)
// before writing those same rows in the epilogue, so this is safe.
// ---------------------------------------------------------------------------
#define KC 32
#define MT 128

__global__ __launch_bounds__(256) void gemm_fused(
    const float* A1, const float* __restrict__ S1,
    const float* __restrict__ B1,
    const float* A2, const float* __restrict__ B2,
    const float* __restrict__ bias, float* out, int M)
{
    __shared__ float As[KC][MT + 4];   // transposed A tile, padded
    __shared__ float Bs[KC][D_H];

    const int t  = threadIdx.x;
    const int tx = t & 15;             // col group (8 cols)
    const int ty = t >> 4;             // row group (8 rows)
    const int row0 = blockIdx.x * MT;

    float acc[8][8];
#pragma unroll
    for (int i = 0; i < 8; i++)
#pragma unroll
        for (int j = 0; j < 8; j++) acc[i][j] = 0.f;

    const int nsrc = A2 ? 2 : 1;
    for (int s = 0; s < nsrc; s++) {
        const float* A = s ? A2 : A1;
        const float* __restrict__ B = s ? B2 : B1;
        const float* __restrict__ S = s ? nullptr : S1;
        for (int k0 = 0; k0 < D_H; k0 += KC) {
            __syncthreads();
#pragma unroll
            for (int it = 0; it < 4; it++) {
                const int lr = (t >> 3) + it * 32;
                const int lk = (t & 7) * 4;
                const int r  = row0 + lr;
                float4 v = make_float4(0.f, 0.f, 0.f, 0.f);
                if (r < M) {
                    v = *(const float4*)&A[(size_t)r * D_H + k0 + lk];
                    if (S) { const float sc = S[r]; v.x *= sc; v.y *= sc; v.z *= sc; v.w *= sc; }
                }
                As[lk + 0][lr] = v.x; As[lk + 1][lr] = v.y;
                As[lk + 2][lr] = v.z; As[lk + 3][lr] = v.w;
            }
#pragma unroll
            for (int it = 0; it < 4; it++) {
                const int kr = (t >> 5) + it * 8;
                const int c  = (t & 31) * 4;
                *(float4*)&Bs[kr][c] = *(const float4*)&B[(size_t)(k0 + kr) * D_H + c];
            }
            __syncthreads();
#pragma unroll 8
            for (int kk = 0; kk < KC; kk++) {
                const float4 a0 = *(const float4*)&As[kk][ty * 8];
                const float4 a1 = *(const float4*)&As[kk][ty * 8 + 4];
                const float4 b0 = *(const float4*)&Bs[kk][tx * 8];
                const float4 b1 = *(const float4*)&Bs[kk][tx * 8 + 4];
                const float a[8] = {a0.x, a0.y, a0.z, a0.w, a1.x, a1.y, a1.z, a1.w};
                const float b[8] = {b0.x, b0.y, b0.z, b0.w, b1.x, b1.y, b1.z, b1.w};
#pragma unroll
                for (int i = 0; i < 8; i++)
#pragma unroll
                    for (int j = 0; j < 8; j++) acc[i][j] += a[i] * b[j];
            }
        }
    }

    float bv[8];
#pragma unroll
    for (int j = 0; j < 8; j++) bv[j] = bias[tx * 8 + j];
#pragma unroll
    for (int i = 0; i < 8; i++) {
        const int r = row0 + ty * 8 + i;
        if (r < M) {
            float4 o0, o1;
            o0.x = fmaxf(acc[i][0] + bv[0], 0.f);
            o0.y = fmaxf(acc[i][1] + bv[1], 0.f);
            o0.z = fmaxf(acc[i][2] + bv[2], 0.f);
            o0.w = fmaxf(acc[i][3] + bv[3], 0.f);
            o1.x = fmaxf(acc[i][4] + bv[4], 0.f);
            o1.y = fmaxf(acc[i][5] + bv[5], 0.f);
            o1.z = fmaxf(acc[i][6] + bv[6], 0.f);
            o1.w = fmaxf(acc[i][7] + bv[7], 0.f);
            *(float4*)&out[(size_t)r * D_H + tx * 8]     = o0;
            *(float4*)&out[(size_t)r * D_H + tx * 8 + 4] = o1;
        }
    }
}

// ---------------------------------------------------------------------------
// CSR build: deg histogram -> exclusive scan -> slot fill
// ---------------------------------------------------------------------------
__global__ __launch_bounds__(256) void deg_kernel(
    const int* __restrict__ dst, int* __restrict__ deg)
{
    const int e = blockIdx.x * blockDim.x + threadIdx.x;
    if (e < N_EDGES) atomicAdd(&deg[dst[e]], 1);
}

__global__ __launch_bounds__(256) void inv_kernel(
    const int* __restrict__ deg, float* __restrict__ inv)
{
    const int n = blockIdx.x * blockDim.x + threadIdx.x;
    if (n < N_NODES) inv[n] = 1.0f / fmaxf((float)deg[n], 1.0f);
}

#define SCAN_ELEMS 1024
#define SCAN_NB    ((N_NODES + SCAN_ELEMS - 1) / SCAN_ELEMS)

__global__ __launch_bounds__(256) void scan_blk(
    const int* __restrict__ deg, int* __restrict__ bsum)
{
    __shared__ int sdata[256];
    const int base = blockIdx.x * SCAN_ELEMS;
    int v = 0;
#pragma unroll
    for (int i = 0; i < 4; i++) {
        const int idx = base + threadIdx.x * 4 + i;
        v += (idx < N_NODES) ? deg[idx] : 0;
    }
    sdata[threadIdx.x] = v; __syncthreads();
    for (int s = 128; s > 0; s >>= 1) {
        if (threadIdx.x < s) sdata[threadIdx.x] += sdata[threadIdx.x + s];
        __syncthreads();
    }
    if (threadIdx.x == 0) bsum[blockIdx.x] = sdata[0];
}

__global__ void scan_top(int* bsum)
{
    int acc = 0;
    for (int i = 0; i < SCAN_NB; i++) { const int t = bsum[i]; bsum[i] = acc; acc += t; }
}

__global__ __launch_bounds__(256) void scan_fin(
    const int* __restrict__ deg, const int* __restrict__ bsum, int* __restrict__ rp)
{
    __shared__ int tsum[256];
    const int base = blockIdx.x * SCAN_ELEMS;
    int loc[4]; int v = 0;
#pragma unroll
    for (int i = 0; i < 4; i++) {
        const int idx = base + threadIdx.x * 4 + i;
        loc[i] = (idx < N_NODES) ? deg[idx] : 0;
        v += loc[i];
    }
    tsum[threadIdx.x] = v; __syncthreads();
    for (int s = 1; s < 256; s <<= 1) {
        const int t = (threadIdx.x >= s) ? tsum[threadIdx.x - s] : 0;
        __syncthreads();
        tsum[threadIdx.x] += t;
        __syncthreads();
    }
    int excl = bsum[blockIdx.x] + ((threadIdx.x > 0) ? tsum[threadIdx.x - 1] : 0);
#pragma unroll
    for (int i = 0; i < 4; i++) {
        const int idx = base + threadIdx.x * 4 + i;
        if (idx < N_NODES) { rp[idx] = excl; excl += loc[i]; }
    }
}

__global__ __launch_bounds__(256) void fill_csr(
    const int* __restrict__ src, const int* __restrict__ dst,
    const int* __restrict__ rp, int* __restrict__ fill, int* __restrict__ csr)
{
    const int e = blockIdx.x * blockDim.x + threadIdx.x;
    if (e < N_EDGES) {
        const int d = dst[e];
        const int pos = atomicAdd(&fill[d], 1);
        csr[rp[d] + pos] = src[e];
    }
}

// ---------------------------------------------------------------------------
// Gather-mean: one wave per dst node; lane owns 2 features (float2).
// agg[n] = (1/max(deg,1)) * sum_{s in csr[n]} h[s]
// ---------------------------------------------------------------------------
__global__ __launch_bounds__(256) void gather_mean(
    const float* __restrict__ h, const int* __restrict__ csr,
    const int* __restrict__ rp, const int* __restrict__ deg,
    const float* __restrict__ inv, float* __restrict__ agg)
{
    const int wave   = (blockIdx.x * blockDim.x + threadIdx.x) >> 6;
    const int lane   = threadIdx.x & 63;
    const int nwaves = (gridDim.x * blockDim.x) >> 6;
    for (int n = wave; n < N_NODES; n += nwaves) {
        const int s0 = rp[n];
        const int s1 = s0 + deg[n];
        float ax = 0.f, ay = 0.f;
        int j = s0;
        for (; j + 1 < s1; j += 2) {
            const int sA = csr[j];
            const int sB = csr[j + 1];
            const float2 vA = *(const float2*)&h[(size_t)sA * D_H + lane * 2];
            const float2 vB = *(const float2*)&h[(size_t)sB * D_H + lane * 2];
            ax += vA.x + vB.x; ay += vA.y + vB.y;
        }
        if (j < s1) {
            const int sA = csr[j];
            const float2 vA = *(const float2*)&h[(size_t)sA * D_H + lane * 2];
            ax += vA.x; ay += vA.y;
        }
        const float sc = inv[n];
        float2 o; o.x = ax * sc; o.y = ay * sc;
        *(float2*)&agg[(size_t)n * D_H + lane * 2] = o;
    }
}

// graph node counts via binary search on sorted batch_idx
__global__ __launch_bounds__(256) void graph_cnt_kernel(
    const int* __restrict__ batch, float* __restrict__ cnt)
{
    const int g = blockIdx.x * blockDim.x + threadIdx.x;
    if (g >= N_GRAPHS) return;
    auto lb = [&](int v) {
        int lo = 0, hi = N_NODES;
        while (lo < hi) { const int m = (lo + hi) >> 1; if (batch[m] < v) lo = m + 1; else hi = m; }
        return lo;
    };
    cnt[g] = (float)(lb(g + 1) - lb(g));
}

// ---------------------------------------------------------------------------
// Pooling: per-thread run-length accumulate (batch_idx sorted)
// ---------------------------------------------------------------------------
#define NPB 512
__global__ __launch_bounds__(256) void pool_kernel(
    const float* __restrict__ h, const int* __restrict__ batch,
    float* __restrict__ sumb, float* __restrict__ maxb)
{
    const int f   = threadIdx.x & 127;
    const int sub = threadIdx.x >> 7;
    const int n0  = blockIdx.x * NPB;
    const int nEnd = min(n0 + NPB, N_NODES);
    float sum = 0.f, mx = 0.f;
    int g = -1;
    for (int n = n0 + sub; n < nEnd; n += 2) {
        const int gb = batch[n];
        if (gb != g) {
            if (g >= 0) {
                atomicAdd(&sumb[g * D_H + f], sum);
                atomicMax((int*)&maxb[g * D_H + f], __float_as_int(mx));
            }
            g = gb; sum = 0.f; mx = 0.f;
        }
        const float v = h[(size_t)n * D_H + f];
        sum += v; mx = fmaxf(mx, v);
    }
    if (g >= 0) {
        atomicAdd(&sumb[g * D_H + f], sum);
        atomicMax((int*)&maxb[g * D_H + f], __float_as_int(mx));
    }
}

// ---------------------------------------------------------------------------
// Head MLP
// ---------------------------------------------------------------------------
__global__ __launch_bounds__(128) void mlp_kernel(
    const float* __restrict__ sumb, const float* __restrict__ maxb,
    const float* __restrict__ cnt,  const float* __restrict__ gf,
    const float* __restrict__ W1, const float* __restrict__ b1,
    const float* __restrict__ W2, const float* __restrict__ b2,
    float* __restrict__ out)
{
    __shared__ float z[2 * D_H + 32];
    __shared__ float z1[D_H];
    const int g = blockIdx.x, t = threadIdx.x;
    const float ic = 1.0f / fmaxf(cnt[g], 1.0f);
    z[t]        = sumb[g * D_H + t] * ic;
    z[D_H + t]  = maxb[g * D_H + t];
    if (t < 32) z[2 * D_H + t] = gf[g * 32 + t];
    __syncthreads();
    float a = b1[t];
    for (int k = 0; k < 2 * D_H + 32; k++) a += z[k] * W1[k * D_H + t];
    a = fmaxf(a, 0.f);
    z1[t] = a;
    __syncthreads();
    float o = b2[t];
    for (int k = 0; k < D_H; k++) o += z1[k] * W2[k * D_H + t];
    out[g * D_H + t] = fmaxf(o, 0.f);
}

// ---------------------------------------------------------------------------
extern "C" void kernel_launch(void* const* d_in, const int* in_sizes, int n_in,
                              void* d_out, int out_size, void* d_ws, size_t ws_size,
                              hipStream_t stream)
{
    const float* x     = (const float*)d_in[0];
    const int*   ei    = (const int*)d_in[1];
    const int*   batch = (const int*)d_in[2];
    const float* gf    = (const float*)d_in[3];
    const float* W_in  = (const float*)d_in[4];
    const float* b_in  = (const float*)d_in[5];
    const float* Wl    = (const float*)d_in[6];
    const float* bl    = (const float*)d_in[7];
    const float* Wr    = (const float*)d_in[8];
    const float* W1    = (const float*)d_in[9];
    const float* b1    = (const float*)d_in[10];
    const float* W2    = (const float*)d_in[11];
    const float* b2    = (const float*)d_in[12];
    float* out = (float*)d_out;

    const int* srcI = ei;
    const int* dstI = ei + N_EDGES;

    char* ws = (char*)d_ws;
    size_t off = 0;
    auto alloc = [&](size_t bytes) {
        char* p = ws + off;
        off += (bytes + 511) / 512 * 512;
        return p;
    };
    const size_t hBytes = (size_t)N_NODES * D_H * sizeof(float);
    float* bufA = (float*)alloc(hBytes);           // h / agg ping-pong
    float* bufB = (float*)alloc(hBytes);
    int*   degI = (int*)alloc(N_NODES * sizeof(int));
    float* inv  = (float*)alloc(N_NODES * sizeof(float));
    int*   rp   = (int*)alloc(N_NODES * sizeof(int));
    int*   fill = (int*)alloc(N_NODES * sizeof(int));
    int*   bsum = (int*)alloc(SCAN_NB * sizeof(int));
    int*   csr  = (int*)alloc((size_t)N_EDGES * sizeof(int));
    float* sumb = (float*)alloc(N_GRAPHS * D_H * sizeof(float));
    float* maxb = (float*)alloc(N_GRAPHS * D_H * sizeof(float));
    float* cnt  = (float*)alloc(N_GRAPHS * sizeof(float));

    hipMemsetAsync(degI, 0, N_NODES * sizeof(int), stream);
    hipMemsetAsync(fill, 0, N_NODES * sizeof(int), stream);
    hipMemsetAsync(sumb, 0, N_GRAPHS * D_H * sizeof(float), stream);
    hipMemsetAsync(maxb, 0, N_GRAPHS * D_H * sizeof(float), stream);

    graph_cnt_kernel<<<(N_GRAPHS + 255) / 256, 256, 0, stream>>>(batch, cnt);
    deg_kernel<<<(N_EDGES + 255) / 256, 256, 0, stream>>>(dstI, degI);
    inv_kernel<<<(N_NODES + 255) / 256, 256, 0, stream>>>(degI, inv);
    scan_blk<<<SCAN_NB, 256, 0, stream>>>(degI, bsum);
    scan_top<<<1, 1, 0, stream>>>(bsum);
    scan_fin<<<SCAN_NB, 256, 0, stream>>>(degI, bsum, rp);
    fill_csr<<<(N_EDGES + 255) / 256, 256, 0, stream>>>(srcI, dstI, rp, fill, csr);

    const int gblocks = (N_NODES + MT - 1) / MT;
    // input projection: x -> bufA
    gemm_fused<<<gblocks, 256, 0, stream>>>(x, nullptr, W_in, nullptr, nullptr, b_in, bufA, N_NODES);

    float* h   = bufA;
    float* agg = bufB;
    for (int l = 0; l < N_LAYERS; l++) {
        gather_mean<<<2048, 256, 0, stream>>>(h, csr, rp, degI, inv, agg);
        // out aliases agg (A1): safe, block-local rows only
        gemm_fused<<<gblocks, 256, 0, stream>>>(agg, nullptr, Wl + (size_t)l * D_H * D_H,
                                                h, Wr + (size_t)l * D_H * D_H,
                                                bl + (size_t)l * D_H, agg, N_NODES);
        float* tmp = h; h = agg; agg = tmp;   // new h is the old agg buffer
    }

    pool_kernel<<<(N_NODES + NPB - 1) / NPB, 256, 0, stream>>>(h, batch, sumb, maxb);
    mlp_kernel<<<N_GRAPHS, 128, 0, stream>>>(sumb, maxb, cnt, gf, W1, b1, W2, b2, out);
}

// Round 3
// 677.424 us; speedup vs baseline: 12.7020x; 1.5105x over previous
//
#include <hip/hip_runtime.h>

#define N_NODES  100000
#define N_EDGES  1600000
#define N_GRAPHS 512
#define D_H      128
#define N_LAYERS 3

typedef __attribute__((ext_vector_type(8))) short bf16x8;
typedef __attribute__((ext_vector_type(4))) float f32x4;

__device__ __forceinline__ unsigned short f2bf(float f) {
    unsigned int u = __float_as_uint(f);
    u += 0x7fffu + ((u >> 16) & 1u);          // RNE
    return (unsigned short)(u >> 16);
}
__device__ __forceinline__ float bf2f(unsigned short h) {
    return __uint_as_float(((unsigned int)h) << 16);
}

// ---------------------------------------------------------------------------
// bf16 MFMA GEMM: out = relu( A0@BT[0:128] (+ A1@BT[128:256]) + bias )
// A0/A1: [M][128] bf16 row-major. BT: [128(N)][Ktot] bf16 (pre-transposed).
// Tile 128x128, 256 thr = 4 waves, 64x64 per wave. out may alias A0 (each
// block reads only its own A0 rows before writing them).
// ---------------------------------------------------------------------------
#define BM  128
#define BKP 72   // 64 + 8 pad (ushorts) -> 144B row stride, uniform banks

__global__ __launch_bounds__(256) void gemm_mfma(
    const unsigned short* A0, const unsigned short* A1,
    const unsigned short* __restrict__ BT,
    const float* __restrict__ bias, unsigned short* out, int M, int Ktot)
{
    __shared__ unsigned short As[BM][BKP];
    __shared__ unsigned short Bs[128][BKP];

    const int t    = threadIdx.x;
    const int wave = t >> 6, lane = t & 63;
    const int wr   = wave >> 1, wc = wave & 1;
    const int row0 = blockIdx.x * BM;

    f32x4 acc[4][4];
#pragma unroll
    for (int m = 0; m < 4; m++)
#pragma unroll
        for (int n = 0; n < 4; n++) acc[m][n] = (f32x4)0.f;

    const int nsteps = Ktot >> 6;
    for (int s = 0; s < nsteps; s++) {
        const unsigned short* Asrc;
        int ka;
        if (s * 64 < 128) { Asrc = A0; ka = s * 64; }
        else              { Asrc = A1; ka = s * 64 - 128; }
        const int kb = s * 64;

        __syncthreads();
#pragma unroll
        for (int it = 0; it < 4; it++) {
            const int idx = t + it * 256;
            const int r = idx >> 3, c8 = (idx & 7) * 8;
            uint4 v = make_uint4(0, 0, 0, 0);
            if (row0 + r < M)
                v = *(const uint4*)&Asrc[(size_t)(row0 + r) * D_H + ka + c8];
            *(uint4*)&As[r][c8] = v;
        }
#pragma unroll
        for (int it = 0; it < 4; it++) {
            const int idx = t + it * 256;
            const int n = idx >> 3, c8 = (idx & 7) * 8;
            uint4 v = *(const uint4*)&BT[(size_t)n * Ktot + kb + c8];
            *(uint4*)&Bs[n][c8] = v;
        }
        __syncthreads();

#pragma unroll
        for (int kk = 0; kk < 64; kk += 32) {
            const int koff = kk + (lane >> 4) * 8;
            bf16x8 af[4], bf[4];
#pragma unroll
            for (int m = 0; m < 4; m++)
                af[m] = *(const bf16x8*)&As[wr * 64 + m * 16 + (lane & 15)][koff];
#pragma unroll
            for (int n = 0; n < 4; n++)
                bf[n] = *(const bf16x8*)&Bs[wc * 64 + n * 16 + (lane & 15)][koff];
#pragma unroll
            for (int m = 0; m < 4; m++)
#pragma unroll
                for (int n = 0; n < 4; n++)
                    acc[m][n] = __builtin_amdgcn_mfma_f32_16x16x32_bf16(
                        af[m], bf[n], acc[m][n], 0, 0, 0);
        }
    }

    float bv[4];
#pragma unroll
    for (int n = 0; n < 4; n++) bv[n] = bias[wc * 64 + n * 16 + (lane & 15)];

#pragma unroll
    for (int m = 0; m < 4; m++) {
#pragma unroll
        for (int j = 0; j < 4; j++) {
            const int row = row0 + wr * 64 + m * 16 + (lane >> 4) * 4 + j;
            if (row < M) {
#pragma unroll
                for (int n = 0; n < 4; n++) {
                    const int col = wc * 64 + n * 16 + (lane & 15);
                    out[(size_t)row * D_H + col] = f2bf(fmaxf(acc[m][n][j] + bv[n], 0.f));
                }
            }
        }
    }
}

// ---------------------------------------------------------------------------
// Prep: x fp32 -> bf16
// ---------------------------------------------------------------------------
__global__ __launch_bounds__(256) void conv_x(
    const float* __restrict__ x, unsigned short* __restrict__ xb)
{
    const int i = blockIdx.x * blockDim.x + threadIdx.x;   // over N*128/4
    const int total = N_NODES * D_H / 4;
    if (i < total) {
        const float4 v = *(const float4*)&x[(size_t)i * 4];
        uint2 o;
        o.x = (unsigned)f2bf(v.x) | ((unsigned)f2bf(v.y) << 16);
        o.y = (unsigned)f2bf(v.z) | ((unsigned)f2bf(v.w) << 16);
        *(uint2*)&xb[(size_t)i * 4] = o;
    }
}

// Prep: transposed bf16 weights. BTin[n][k]=W_in[k][n];
// BTl[l][n][k] = k<128 ? Wl[l][k][n] : Wr[l][k-128][n]
__global__ __launch_bounds__(256) void prep_bt(
    const float* __restrict__ W_in, const float* __restrict__ Wl,
    const float* __restrict__ Wr, unsigned short* __restrict__ BTin,
    unsigned short* __restrict__ BTl)
{
    const int i = blockIdx.x * blockDim.x + threadIdx.x;
    if (i < 128 * 128) {
        const int n = i >> 7, k = i & 127;
        BTin[n * 128 + k] = f2bf(W_in[k * 128 + n]);
    } else if (i < 128 * 128 + N_LAYERS * 128 * 256) {
        const int j = i - 128 * 128;
        const int l = j >> 15, r = j & 32767;
        const int n = r >> 8, k = r & 255;
        const float v = (k < 128) ? Wl[(size_t)l * 16384 + k * 128 + n]
                                  : Wr[(size_t)l * 16384 + (k - 128) * 128 + n];
        BTl[(size_t)l * 32768 + n * 256 + k] = f2bf(v);
    }
}

// ---------------------------------------------------------------------------
// CSR build
// ---------------------------------------------------------------------------
__global__ __launch_bounds__(256) void deg_kernel(
    const int* __restrict__ dst, int* __restrict__ deg)
{
    const int e = blockIdx.x * blockDim.x + threadIdx.x;
    if (e < N_EDGES) atomicAdd(&deg[dst[e]], 1);
}

__global__ __launch_bounds__(256) void inv_kernel(
    const int* __restrict__ deg, float* __restrict__ inv)
{
    const int n = blockIdx.x * blockDim.x + threadIdx.x;
    if (n < N_NODES) inv[n] = 1.0f / fmaxf((float)deg[n], 1.0f);
}

#define SCAN_ELEMS 1024
#define SCAN_NB    ((N_NODES + SCAN_ELEMS - 1) / SCAN_ELEMS)

__global__ __launch_bounds__(256) void scan_blk(
    const int* __restrict__ deg, int* __restrict__ bsum)
{
    __shared__ int sdata[256];
    const int base = blockIdx.x * SCAN_ELEMS;
    int v = 0;
#pragma unroll
    for (int i = 0; i < 4; i++) {
        const int idx = base + threadIdx.x * 4 + i;
        v += (idx < N_NODES) ? deg[idx] : 0;
    }
    sdata[threadIdx.x] = v; __syncthreads();
    for (int s = 128; s > 0; s >>= 1) {
        if (threadIdx.x < s) sdata[threadIdx.x] += sdata[threadIdx.x + s];
        __syncthreads();
    }
    if (threadIdx.x == 0) bsum[blockIdx.x] = sdata[0];
}

__global__ void scan_top(int* bsum)
{
    int acc = 0;
    for (int i = 0; i < SCAN_NB; i++) { const int t = bsum[i]; bsum[i] = acc; acc += t; }
}

__global__ __launch_bounds__(256) void scan_fin(
    const int* __restrict__ deg, const int* __restrict__ bsum, int* __restrict__ rp)
{
    __shared__ int tsum[256];
    const int base = blockIdx.x * SCAN_ELEMS;
    int loc[4]; int v = 0;
#pragma unroll
    for (int i = 0; i < 4; i++) {
        const int idx = base + threadIdx.x * 4 + i;
        loc[i] = (idx < N_NODES) ? deg[idx] : 0;
        v += loc[i];
    }
    tsum[threadIdx.x] = v; __syncthreads();
    for (int s = 1; s < 256; s <<= 1) {
        const int t = (threadIdx.x >= s) ? tsum[threadIdx.x - s] : 0;
        __syncthreads();
        tsum[threadIdx.x] += t;
        __syncthreads();
    }
    int excl = bsum[blockIdx.x] + ((threadIdx.x > 0) ? tsum[threadIdx.x - 1] : 0);
#pragma unroll
    for (int i = 0; i < 4; i++) {
        const int idx = base + threadIdx.x * 4 + i;
        if (idx < N_NODES) { rp[idx] = excl; excl += loc[i]; }
    }
}

__global__ __launch_bounds__(256) void fill_csr(
    const int* __restrict__ src, const int* __restrict__ dst,
    const int* __restrict__ rp, int* __restrict__ fill, int* __restrict__ csr)
{
    const int e = blockIdx.x * blockDim.x + threadIdx.x;
    if (e < N_EDGES) {
        const int d = dst[e];
        const int pos = atomicAdd(&fill[d], 1);
        csr[rp[d] + pos] = src[e];
    }
}

// ---------------------------------------------------------------------------
// Gather-mean over bf16 h: one wave per node, lane owns 2 features (uint)
// ---------------------------------------------------------------------------
__global__ __launch_bounds__(256) void gather_mean(
    const unsigned short* __restrict__ h, const int* __restrict__ csr,
    const int* __restrict__ rp, const int* __restrict__ deg,
    const float* __restrict__ inv, unsigned short* __restrict__ agg)
{
    const int wave   = (blockIdx.x * blockDim.x + threadIdx.x) >> 6;
    const int lane   = threadIdx.x & 63;
    const int nwaves = (gridDim.x * blockDim.x) >> 6;
    for (int n = wave; n < N_NODES; n += nwaves) {
        const int s0 = rp[n];
        const int s1 = s0 + deg[n];
        float ax = 0.f, ay = 0.f;
        int j = s0;
        for (; j + 1 < s1; j += 2) {
            const unsigned vA = *(const unsigned*)&h[(size_t)csr[j] * D_H + lane * 2];
            const unsigned vB = *(const unsigned*)&h[(size_t)csr[j + 1] * D_H + lane * 2];
            ax += __uint_as_float(vA << 16) + __uint_as_float(vB << 16);
            ay += __uint_as_float(vA & 0xffff0000u) + __uint_as_float(vB & 0xffff0000u);
        }
        if (j < s1) {
            const unsigned vA = *(const unsigned*)&h[(size_t)csr[j] * D_H + lane * 2];
            ax += __uint_as_float(vA << 16);
            ay += __uint_as_float(vA & 0xffff0000u);
        }
        const float sc = inv[n];
        const unsigned o = (unsigned)f2bf(ax * sc) | ((unsigned)f2bf(ay * sc) << 16);
        *(unsigned*)&agg[(size_t)n * D_H + lane * 2] = o;
    }
}

// graph node counts via binary search on sorted batch_idx
__global__ __launch_bounds__(256) void graph_cnt_kernel(
    const int* __restrict__ batch, float* __restrict__ cnt)
{
    const int g = blockIdx.x * blockDim.x + threadIdx.x;
    if (g >= N_GRAPHS) return;
    auto lb = [&](int v) {
        int lo = 0, hi = N_NODES;
        while (lo < hi) { const int m = (lo + hi) >> 1; if (batch[m] < v) lo = m + 1; else hi = m; }
        return lo;
    };
    cnt[g] = (float)(lb(g + 1) - lb(g));
}

// ---------------------------------------------------------------------------
// Pooling on bf16 h: run-length accumulate (batch sorted)
// ---------------------------------------------------------------------------
#define NPB 512
__global__ __launch_bounds__(256) void pool_kernel(
    const unsigned short* __restrict__ h, const int* __restrict__ batch,
    float* __restrict__ sumb, float* __restrict__ maxb)
{
    const int f   = threadIdx.x & 127;
    const int sub = threadIdx.x >> 7;
    const int n0  = blockIdx.x * NPB;
    const int nEnd = min(n0 + NPB, N_NODES);
    float sum = 0.f, mx = 0.f;
    int g = -1;
    for (int n = n0 + sub; n < nEnd; n += 2) {
        const int gb = batch[n];
        if (gb != g) {
            if (g >= 0) {
                atomicAdd(&sumb[g * D_H + f], sum);
                atomicMax((int*)&maxb[g * D_H + f], __float_as_int(mx));
            }
            g = gb; sum = 0.f; mx = 0.f;
        }
        const float v = bf2f(h[(size_t)n * D_H + f]);
        sum += v; mx = fmaxf(mx, v);
    }
    if (g >= 0) {
        atomicAdd(&sumb[g * D_H + f], sum);
        atomicMax((int*)&maxb[g * D_H + f], __float_as_int(mx));
    }
}

// ---------------------------------------------------------------------------
// Head MLP (fp32)
// ---------------------------------------------------------------------------
__global__ __launch_bounds__(128) void mlp_kernel(
    const float* __restrict__ sumb, const float* __restrict__ maxb,
    const float* __restrict__ cnt,  const float* __restrict__ gf,
    const float* __restrict__ W1, const float* __restrict__ b1,
    const float* __restrict__ W2, const float* __restrict__ b2,
    float* __restrict__ out)
{
    __shared__ float z[2 * D_H + 32];
    __shared__ float z1[D_H];
    const int g = blockIdx.x, t = threadIdx.x;
    const float ic = 1.0f / fmaxf(cnt[g], 1.0f);
    z[t]        = sumb[g * D_H + t] * ic;
    z[D_H + t]  = maxb[g * D_H + t];
    if (t < 32) z[2 * D_H + t] = gf[g * 32 + t];
    __syncthreads();
    float a = b1[t];
    for (int k = 0; k < 2 * D_H + 32; k++) a += z[k] * W1[k * D_H + t];
    a = fmaxf(a, 0.f);
    z1[t] = a;
    __syncthreads();
    float o = b2[t];
    for (int k = 0; k < D_H; k++) o += z1[k] * W2[k * D_H + t];
    out[g * D_H + t] = fmaxf(o, 0.f);
}

// ---------------------------------------------------------------------------
extern "C" void kernel_launch(void* const* d_in, const int* in_sizes, int n_in,
                              void* d_out, int out_size, void* d_ws, size_t ws_size,
                              hipStream_t stream)
{
    const float* x     = (const float*)d_in[0];
    const int*   ei    = (const int*)d_in[1];
    const int*   batch = (const int*)d_in[2];
    const float* gf    = (const float*)d_in[3];
    const float* W_in  = (const float*)d_in[4];
    const float* b_in  = (const float*)d_in[5];
    const float* Wl    = (const float*)d_in[6];
    const float* bl    = (const float*)d_in[7];
    const float* Wr    = (const float*)d_in[8];
    const float* W1    = (const float*)d_in[9];
    const float* b1    = (const float*)d_in[10];
    const float* W2    = (const float*)d_in[11];
    const float* b2    = (const float*)d_in[12];
    float* out = (float*)d_out;

    const int* srcI = ei;
    const int* dstI = ei + N_EDGES;

    char* ws = (char*)d_ws;
    size_t off = 0;
    auto alloc = [&](size_t bytes) {
        char* p = ws + off;
        off += (bytes + 511) / 512 * 512;
        return p;
    };
    const size_t hB16 = (size_t)N_NODES * D_H * sizeof(unsigned short);
    unsigned short* xb   = (unsigned short*)alloc(hB16);
    unsigned short* bufA = (unsigned short*)alloc(hB16);
    unsigned short* bufB = (unsigned short*)alloc(hB16);
    unsigned short* BTin = (unsigned short*)alloc(128 * 128 * sizeof(unsigned short));
    unsigned short* BTl  = (unsigned short*)alloc((size_t)N_LAYERS * 128 * 256 * sizeof(unsigned short));
    int*   degI = (int*)alloc(N_NODES * sizeof(int));
    float* inv  = (float*)alloc(N_NODES * sizeof(float));
    int*   rp   = (int*)alloc(N_NODES * sizeof(int));
    int*   fill = (int*)alloc(N_NODES * sizeof(int));
    int*   bsum = (int*)alloc(SCAN_NB * sizeof(int));
    int*   csr  = (int*)alloc((size_t)N_EDGES * sizeof(int));
    float* sumb = (float*)alloc(N_GRAPHS * D_H * sizeof(float));
    float* maxb = (float*)alloc(N_GRAPHS * D_H * sizeof(float));
    float* cnt  = (float*)alloc(N_GRAPHS * sizeof(float));

    hipMemsetAsync(degI, 0, N_NODES * sizeof(int), stream);
    hipMemsetAsync(fill, 0, N_NODES * sizeof(int), stream);
    hipMemsetAsync(sumb, 0, N_GRAPHS * D_H * sizeof(float), stream);
    hipMemsetAsync(maxb, 0, N_GRAPHS * D_H * sizeof(float), stream);

    graph_cnt_kernel<<<(N_GRAPHS + 255) / 256, 256, 0, stream>>>(batch, cnt);
    deg_kernel<<<(N_EDGES + 255) / 256, 256, 0, stream>>>(dstI, degI);
    inv_kernel<<<(N_NODES + 255) / 256, 256, 0, stream>>>(degI, inv);
    scan_blk<<<SCAN_NB, 256, 0, stream>>>(degI, bsum);
    scan_top<<<1, 1, 0, stream>>>(bsum);
    scan_fin<<<SCAN_NB, 256, 0, stream>>>(degI, bsum, rp);
    fill_csr<<<(N_EDGES + 255) / 256, 256, 0, stream>>>(srcI, dstI, rp, fill, csr);

    conv_x<<<(N_NODES * D_H / 4 + 255) / 256, 256, 0, stream>>>(x, xb);
    prep_bt<<<(128 * 128 + N_LAYERS * 128 * 256 + 255) / 256, 256, 0, stream>>>(
        W_in, Wl, Wr, BTin, BTl);

    const int gblocks = (N_NODES + BM - 1) / BM;
    // input projection: xb -> bufA
    gemm_mfma<<<gblocks, 256, 0, stream>>>(xb, nullptr, BTin, b_in, bufA, N_NODES, 128);

    unsigned short* h   = bufA;
    unsigned short* agg = bufB;
    for (int l = 0; l < N_LAYERS; l++) {
        gather_mean<<<2048, 256, 0, stream>>>(h, csr, rp, degI, inv, agg);
        gemm_mfma<<<gblocks, 256, 0, stream>>>(agg, h, BTl + (size_t)l * 32768,
                                               bl + (size_t)l * D_H, agg, N_NODES, 256);
        unsigned short* tmp = h; h = agg; agg = tmp;
    }

    pool_kernel<<<(N_NODES + NPB - 1) / NPB, 256, 0, stream>>>(h, batch, sumb, maxb);
    mlp_kernel<<<N_GRAPHS, 128, 0, stream>>>(sumb, maxb, cnt, gf, W1, b1, W2, b2, out);
}

// Round 4
// 546.340 us; speedup vs baseline: 15.7496x; 1.2399x over previous
//
#include <hip/hip_runtime.h>

#define N_NODES  100000
#define N_EDGES  1600000
#define N_GRAPHS 512
#define D_H      128
#define N_LAYERS 3

typedef __attribute__((ext_vector_type(8))) short bf16x8;
typedef __attribute__((ext_vector_type(4))) float f32x4;

__device__ __forceinline__ unsigned short f2bf(float f) {
    unsigned int u = __float_as_uint(f);
    u += 0x7fffu + ((u >> 16) & 1u);          // RNE
    return (unsigned short)(u >> 16);
}
__device__ __forceinline__ float bf2f(unsigned short h) {
    return __uint_as_float(((unsigned int)h) << 16);
}

// ---------------------------------------------------------------------------
// bf16 MFMA GEMM, 128x128 tile, 4 waves (64x64/wave), K staged 64 at a time.
// MODE 0: A = Af (fp32, Ktot=128), converted to bf16 during staging.
// MODE 1: A = concat-K [A0 | A1] (bf16, Ktot=256).  out may alias A0.
// BT: [128(N)][Ktot] bf16 pre-transposed.
// ---------------------------------------------------------------------------
#define BM  128
#define BKP 72   // 64 + 8 pad ushorts

template <int MODE>
__global__ __launch_bounds__(256) void gemm_mfma(
    const float* __restrict__ Af, const unsigned short* A0,
    const unsigned short* A1, const unsigned short* __restrict__ BT,
    const float* __restrict__ bias, unsigned short* out, int M)
{
    constexpr int Ktot = (MODE == 0) ? 128 : 256;
    __shared__ unsigned short As[BM][BKP];
    __shared__ unsigned short Bs[128][BKP];

    const int t    = threadIdx.x;
    const int wave = t >> 6, lane = t & 63;
    const int wr   = wave >> 1, wc = wave & 1;
    const int row0 = blockIdx.x * BM;

    f32x4 acc[4][4];
#pragma unroll
    for (int m = 0; m < 4; m++)
#pragma unroll
        for (int n = 0; n < 4; n++) acc[m][n] = (f32x4)0.f;

    for (int s = 0; s < (Ktot >> 6); s++) {
        const int kb = s * 64;
        __syncthreads();
        if (MODE == 0) {
#pragma unroll
            for (int it = 0; it < 4; it++) {
                const int idx = t + it * 256;
                const int r = idx >> 3, c8 = (idx & 7) * 8;
                uint4 o = make_uint4(0, 0, 0, 0);
                if (row0 + r < M) {
                    const float* p = &Af[(size_t)(row0 + r) * D_H + kb + c8];
                    const float4 v0 = *(const float4*)p;
                    const float4 v1 = *(const float4*)(p + 4);
                    o.x = (unsigned)f2bf(v0.x) | ((unsigned)f2bf(v0.y) << 16);
                    o.y = (unsigned)f2bf(v0.z) | ((unsigned)f2bf(v0.w) << 16);
                    o.z = (unsigned)f2bf(v1.x) | ((unsigned)f2bf(v1.y) << 16);
                    o.w = (unsigned)f2bf(v1.z) | ((unsigned)f2bf(v1.w) << 16);
                }
                *(uint4*)&As[r][c8] = o;
            }
        } else {
            const unsigned short* Asrc = (kb < 128) ? A0 : A1;
            const int ka = kb & 127;
#pragma unroll
            for (int it = 0; it < 4; it++) {
                const int idx = t + it * 256;
                const int r = idx >> 3, c8 = (idx & 7) * 8;
                uint4 v = make_uint4(0, 0, 0, 0);
                if (row0 + r < M)
                    v = *(const uint4*)&Asrc[(size_t)(row0 + r) * D_H + ka + c8];
                *(uint4*)&As[r][c8] = v;
            }
        }
#pragma unroll
        for (int it = 0; it < 4; it++) {
            const int idx = t + it * 256;
            const int n = idx >> 3, c8 = (idx & 7) * 8;
            *(uint4*)&Bs[n][c8] = *(const uint4*)&BT[(size_t)n * Ktot + kb + c8];
        }
        __syncthreads();

#pragma unroll
        for (int kk = 0; kk < 64; kk += 32) {
            const int koff = kk + (lane >> 4) * 8;
            bf16x8 af[4], bfr[4];
#pragma unroll
            for (int m = 0; m < 4; m++)
                af[m] = *(const bf16x8*)&As[wr * 64 + m * 16 + (lane & 15)][koff];
#pragma unroll
            for (int n = 0; n < 4; n++)
                bfr[n] = *(const bf16x8*)&Bs[wc * 64 + n * 16 + (lane & 15)][koff];
#pragma unroll
            for (int m = 0; m < 4; m++)
#pragma unroll
                for (int n = 0; n < 4; n++)
                    acc[m][n] = __builtin_amdgcn_mfma_f32_16x16x32_bf16(
                        af[m], bfr[n], acc[m][n], 0, 0, 0);
        }
    }

    float bv[4];
#pragma unroll
    for (int n = 0; n < 4; n++) bv[n] = bias[wc * 64 + n * 16 + (lane & 15)];

#pragma unroll
    for (int m = 0; m < 4; m++) {
#pragma unroll
        for (int j = 0; j < 4; j++) {
            const int row = row0 + wr * 64 + m * 16 + (lane >> 4) * 4 + j;
            if (row < M) {
#pragma unroll
                for (int n = 0; n < 4; n++) {
                    const int col = wc * 64 + n * 16 + (lane & 15);
                    out[(size_t)row * D_H + col] = f2bf(fmaxf(acc[m][n][j] + bv[n], 0.f));
                }
            }
        }
    }
}

// ---------------------------------------------------------------------------
// Weight prep: transposed bf16 weights
// ---------------------------------------------------------------------------
__global__ __launch_bounds__(256) void prep_bt(
    const float* __restrict__ W_in, const float* __restrict__ Wl,
    const float* __restrict__ Wr, unsigned short* __restrict__ BTin,
    unsigned short* __restrict__ BTl)
{
    const int i = blockIdx.x * blockDim.x + threadIdx.x;
    if (i < 128 * 128) {
        const int n = i >> 7, k = i & 127;
        BTin[n * 128 + k] = f2bf(W_in[k * 128 + n]);
    } else if (i < 128 * 128 + N_LAYERS * 128 * 256) {
        const int j = i - 128 * 128;
        const int l = j >> 15, r = j & 32767;
        const int n = r >> 8, k = r & 255;
        const float v = (k < 128) ? Wl[(size_t)l * 16384 + k * 128 + n]
                                  : Wr[(size_t)l * 16384 + (k - 128) * 128 + n];
        BTl[(size_t)l * 32768 + n * 256 + k] = f2bf(v);
    }
}

// ---------------------------------------------------------------------------
// CSR build via 256-bucket binning (bucket = dst>>9, 512 nodes each).
// No global atomics; scattered writes confined to L2-hot bucket regions.
// ---------------------------------------------------------------------------
#define NBUK 256
#define EPB  8192
#define NBLK ((N_EDGES + EPB - 1) / EPB)     // 196

__global__ __launch_bounds__(256) void csr_count(
    const int* __restrict__ dst, int* __restrict__ cntMat)
{
    __shared__ int cnt[NBUK];
    cnt[threadIdx.x] = 0;
    __syncthreads();
    const int e0 = blockIdx.x * EPB;
    const int e1 = min(e0 + EPB, N_EDGES);
    for (int e = e0 + threadIdx.x; e < e1; e += 256)
        atomicAdd(&cnt[dst[e] >> 9], 1);
    __syncthreads();
    cntMat[threadIdx.x * NBLK + blockIdx.x] = cnt[threadIdx.x];
}

// per-bucket exclusive scan over blocks
__global__ __launch_bounds__(256) void csr_scan_bucket(
    const int* __restrict__ cntMat, int* __restrict__ basMat, int* __restrict__ btot)
{
    __shared__ int s[256];
    const int b = blockIdx.x, t = threadIdx.x;
    const int v = (t < NBLK) ? cntMat[b * NBLK + t] : 0;
    s[t] = v; __syncthreads();
    for (int st = 1; st < 256; st <<= 1) {
        const int u = (t >= st) ? s[t - st] : 0;
        __syncthreads();
        s[t] += u;
        __syncthreads();
    }
    if (t < NBLK) basMat[b * NBLK + t] = s[t] - v;
    if (t == 255) btot[b] = s[255];
}

__global__ __launch_bounds__(256) void csr_scan_top(
    const int* __restrict__ btot, int* __restrict__ bbase)
{
    __shared__ int s[NBUK];
    const int t = threadIdx.x;
    const int v = btot[t];
    s[t] = v; __syncthreads();
    for (int st = 1; st < 256; st <<= 1) {
        const int u = (t >= st) ? s[t - st] : 0;
        __syncthreads();
        s[t] += u;
        __syncthreads();
    }
    bbase[t] = s[t] - v;
}

__global__ __launch_bounds__(256) void csr_scatter(
    const int* __restrict__ src, const int* __restrict__ dst,
    const int* __restrict__ basMat, const int* __restrict__ bbase,
    int2* __restrict__ binned)
{
    __shared__ int cur[NBUK];
    cur[threadIdx.x] = bbase[threadIdx.x] + basMat[threadIdx.x * NBLK + blockIdx.x];
    __syncthreads();
    const int e0 = blockIdx.x * EPB;
    const int e1 = min(e0 + EPB, N_EDGES);
    for (int e = e0 + threadIdx.x; e < e1; e += 256) {
        const int d = dst[e];
        const int pos = atomicAdd(&cur[d >> 9], 1);
        binned[pos] = make_int2(src[e], d);
    }
}

// one block per bucket: local histogram -> deg/rp/inv + csr fill
__global__ __launch_bounds__(256) void csr_build(
    const int2* __restrict__ binned, const int* __restrict__ bbase,
    const int* __restrict__ btot, int* __restrict__ rp, int* __restrict__ deg,
    float* __restrict__ inv, int* __restrict__ csr)
{
    __shared__ int hist[512];
    __shared__ int psc[256];
    __shared__ int cur[512];
    const int b = blockIdx.x, t = threadIdx.x;
    const int base = bbase[b];
    const int cntE = btot[b];
    const int n0 = b << 9;

    hist[t] = 0; hist[t + 256] = 0;
    __syncthreads();
    for (int i = t; i < cntE; i += 256)
        atomicAdd(&hist[binned[base + i].y - n0], 1);
    __syncthreads();

    const int h0 = hist[2 * t], h1 = hist[2 * t + 1];
    const int own = h0 + h1;
    psc[t] = own; __syncthreads();
    for (int st = 1; st < 256; st <<= 1) {
        const int u = (t >= st) ? psc[t - st] : 0;
        __syncthreads();
        psc[t] += u;
        __syncthreads();
    }
    const int pairExcl = psc[t] - own;
    cur[2 * t]     = pairExcl;
    cur[2 * t + 1] = pairExcl + h0;
    const int node0 = n0 + 2 * t, node1 = n0 + 2 * t + 1;
    if (node0 < N_NODES) {
        rp[node0] = base + pairExcl; deg[node0] = h0;
        inv[node0] = 1.f / fmaxf((float)h0, 1.f);
    }
    if (node1 < N_NODES) {
        rp[node1] = base + pairExcl + h0; deg[node1] = h1;
        inv[node1] = 1.f / fmaxf((float)h1, 1.f);
    }
    __syncthreads();
    for (int i = t; i < cntE; i += 256) {
        const int2 r = binned[base + i];
        const int pos = atomicAdd(&cur[r.y - n0], 1);
        csr[base + pos] = r.x;
    }
}

// ---------------------------------------------------------------------------
// Gather-mean over bf16 h: one wave per node, lane owns 2 features (uint)
// ---------------------------------------------------------------------------
__global__ __launch_bounds__(256) void gather_mean(
    const unsigned short* __restrict__ h, const int* __restrict__ csr,
    const int* __restrict__ rp, const int* __restrict__ deg,
    const float* __restrict__ inv, unsigned short* __restrict__ agg)
{
    const int wave   = (blockIdx.x * blockDim.x + threadIdx.x) >> 6;
    const int lane   = threadIdx.x & 63;
    const int nwaves = (gridDim.x * blockDim.x) >> 6;
    for (int n = wave; n < N_NODES; n += nwaves) {
        const int s0 = rp[n];
        const int s1 = s0 + deg[n];
        float ax = 0.f, ay = 0.f;
        int j = s0;
        for (; j + 1 < s1; j += 2) {
            const unsigned vA = *(const unsigned*)&h[(size_t)csr[j] * D_H + lane * 2];
            const unsigned vB = *(const unsigned*)&h[(size_t)csr[j + 1] * D_H + lane * 2];
            ax += __uint_as_float(vA << 16) + __uint_as_float(vB << 16);
            ay += __uint_as_float(vA & 0xffff0000u) + __uint_as_float(vB & 0xffff0000u);
        }
        if (j < s1) {
            const unsigned vA = *(const unsigned*)&h[(size_t)csr[j] * D_H + lane * 2];
            ax += __uint_as_float(vA << 16);
            ay += __uint_as_float(vA & 0xffff0000u);
        }
        const float sc = inv[n];
        const unsigned o = (unsigned)f2bf(ax * sc) | ((unsigned)f2bf(ay * sc) << 16);
        *(unsigned*)&agg[(size_t)n * D_H + lane * 2] = o;
    }
}

// graph node counts via binary search on sorted batch_idx
__global__ __launch_bounds__(256) void graph_cnt_kernel(
    const int* __restrict__ batch, float* __restrict__ cnt)
{
    const int g = blockIdx.x * blockDim.x + threadIdx.x;
    if (g >= N_GRAPHS) return;
    auto lb = [&](int v) {
        int lo = 0, hi = N_NODES;
        while (lo < hi) { const int m = (lo + hi) >> 1; if (batch[m] < v) lo = m + 1; else hi = m; }
        return lo;
    };
    cnt[g] = (float)(lb(g + 1) - lb(g));
}

// ---------------------------------------------------------------------------
// Pooling on bf16 h: run-length accumulate (batch sorted)
// ---------------------------------------------------------------------------
#define NPB 512
__global__ __launch_bounds__(256) void pool_kernel(
    const unsigned short* __restrict__ h, const int* __restrict__ batch,
    float* __restrict__ sumb, float* __restrict__ maxb)
{
    const int f   = threadIdx.x & 127;
    const int sub = threadIdx.x >> 7;
    const int n0  = blockIdx.x * NPB;
    const int nEnd = min(n0 + NPB, N_NODES);
    float sum = 0.f, mx = 0.f;
    int g = -1;
    for (int n = n0 + sub; n < nEnd; n += 2) {
        const int gb = batch[n];
        if (gb != g) {
            if (g >= 0) {
                atomicAdd(&sumb[g * D_H + f], sum);
                atomicMax((int*)&maxb[g * D_H + f], __float_as_int(mx));
            }
            g = gb; sum = 0.f; mx = 0.f;
        }
        const float v = bf2f(h[(size_t)n * D_H + f]);
        sum += v; mx = fmaxf(mx, v);
    }
    if (g >= 0) {
        atomicAdd(&sumb[g * D_H + f], sum);
        atomicMax((int*)&maxb[g * D_H + f], __float_as_int(mx));
    }
}

// ---------------------------------------------------------------------------
// Head MLP (fp32)
// ---------------------------------------------------------------------------
__global__ __launch_bounds__(128) void mlp_kernel(
    const float* __restrict__ sumb, const float* __restrict__ maxb,
    const float* __restrict__ cnt,  const float* __restrict__ gf,
    const float* __restrict__ W1, const float* __restrict__ b1,
    const float* __restrict__ W2, const float* __restrict__ b2,
    float* __restrict__ out)
{
    __shared__ float z[2 * D_H + 32];
    __shared__ float z1[D_H];
    const int g = blockIdx.x, t = threadIdx.x;
    const float ic = 1.0f / fmaxf(cnt[g], 1.0f);
    z[t]        = sumb[g * D_H + t] * ic;
    z[D_H + t]  = maxb[g * D_H + t];
    if (t < 32) z[2 * D_H + t] = gf[g * 32 + t];
    __syncthreads();
    float a = b1[t];
    for (int k = 0; k < 2 * D_H + 32; k++) a += z[k] * W1[k * D_H + t];
    a = fmaxf(a, 0.f);
    z1[t] = a;
    __syncthreads();
    float o = b2[t];
    for (int k = 0; k < D_H; k++) o += z1[k] * W2[k * D_H + t];
    out[g * D_H + t] = fmaxf(o, 0.f);
}

// ---------------------------------------------------------------------------
extern "C" void kernel_launch(void* const* d_in, const int* in_sizes, int n_in,
                              void* d_out, int out_size, void* d_ws, size_t ws_size,
                              hipStream_t stream)
{
    const float* x     = (const float*)d_in[0];
    const int*   ei    = (const int*)d_in[1];
    const int*   batch = (const int*)d_in[2];
    const float* gf    = (const float*)d_in[3];
    const float* W_in  = (const float*)d_in[4];
    const float* b_in  = (const float*)d_in[5];
    const float* Wl    = (const float*)d_in[6];
    const float* bl    = (const float*)d_in[7];
    const float* Wr    = (const float*)d_in[8];
    const float* W1    = (const float*)d_in[9];
    const float* b1    = (const float*)d_in[10];
    const float* W2    = (const float*)d_in[11];
    const float* b2    = (const float*)d_in[12];
    float* out = (float*)d_out;

    const int* srcI = ei;
    const int* dstI = ei + N_EDGES;

    char* ws = (char*)d_ws;
    size_t off = 0;
    auto alloc = [&](size_t bytes) {
        char* p = ws + off;
        off += (bytes + 511) / 512 * 512;
        return p;
    };
    const size_t hB16 = (size_t)N_NODES * D_H * sizeof(unsigned short);
    unsigned short* bufA = (unsigned short*)alloc(hB16);
    unsigned short* bufB = (unsigned short*)alloc(hB16);
    unsigned short* BTin = (unsigned short*)alloc(128 * 128 * sizeof(unsigned short));
    unsigned short* BTl  = (unsigned short*)alloc((size_t)N_LAYERS * 128 * 256 * sizeof(unsigned short));
    int*   degI   = (int*)alloc(N_NODES * sizeof(int));
    float* inv    = (float*)alloc(N_NODES * sizeof(float));
    int*   rp     = (int*)alloc(N_NODES * sizeof(int));
    int*   csr    = (int*)alloc((size_t)N_EDGES * sizeof(int));
    int2*  binned = (int2*)alloc((size_t)N_EDGES * sizeof(int2));
    int*   cntMat = (int*)alloc((size_t)NBUK * NBLK * sizeof(int));
    int*   basMat = (int*)alloc((size_t)NBUK * NBLK * sizeof(int));
    int*   btot   = (int*)alloc(NBUK * sizeof(int));
    int*   bbase  = (int*)alloc(NBUK * sizeof(int));
    float* sumb   = (float*)alloc(N_GRAPHS * D_H * sizeof(float));
    float* maxb   = (float*)alloc(N_GRAPHS * D_H * sizeof(float));
    float* cnt    = (float*)alloc(N_GRAPHS * sizeof(float));

    hipMemsetAsync(sumb, 0, N_GRAPHS * D_H * sizeof(float), stream);
    hipMemsetAsync(maxb, 0, N_GRAPHS * D_H * sizeof(float), stream);

    graph_cnt_kernel<<<(N_GRAPHS + 255) / 256, 256, 0, stream>>>(batch, cnt);

    // CSR build (atomic-free, binned)
    csr_count<<<NBLK, 256, 0, stream>>>(dstI, cntMat);
    csr_scan_bucket<<<NBUK, 256, 0, stream>>>(cntMat, basMat, btot);
    csr_scan_top<<<1, 256, 0, stream>>>(btot, bbase);
    csr_scatter<<<NBLK, 256, 0, stream>>>(srcI, dstI, basMat, bbase, binned);
    csr_build<<<NBUK, 256, 0, stream>>>(binned, bbase, btot, rp, degI, inv, csr);

    prep_bt<<<(128 * 128 + N_LAYERS * 128 * 256 + 255) / 256, 256, 0, stream>>>(
        W_in, Wl, Wr, BTin, BTl);

    const int gblocks = (N_NODES + BM - 1) / BM;
    // input projection (fp32 x converted in staging): -> bufA
    gemm_mfma<0><<<gblocks, 256, 0, stream>>>(x, nullptr, nullptr, BTin, b_in, bufA, N_NODES);

    unsigned short* h   = bufA;
    unsigned short* agg = bufB;
    for (int l = 0; l < N_LAYERS; l++) {
        gather_mean<<<2048, 256, 0, stream>>>(h, csr, rp, degI, inv, agg);
        gemm_mfma<1><<<gblocks, 256, 0, stream>>>(nullptr, agg, h, BTl + (size_t)l * 32768,
                                                  bl + (size_t)l * D_H, agg, N_NODES);
        unsigned short* tmp = h; h = agg; agg = tmp;
    }

    pool_kernel<<<(N_NODES + NPB - 1) / NPB, 256, 0, stream>>>(h, batch, sumb, maxb);
    mlp_kernel<<<N_GRAPHS, 128, 0, stream>>>(sumb, maxb, cnt, gf, W1, b1, W2, b2, out);
}

// Round 5
// 465.637 us; speedup vs baseline: 18.4793x; 1.1733x over previous
//
#include <hip/hip_runtime.h>

#define N_NODES  100000
#define N_EDGES  1600000
#define N_GRAPHS 512
#define D_H      128
#define N_LAYERS 3

typedef __attribute__((ext_vector_type(8))) short bf16x8;
typedef __attribute__((ext_vector_type(4))) float f32x4;

__device__ __forceinline__ unsigned short f2bf(float f) {
    unsigned int u = __float_as_uint(f);
    u += 0x7fffu + ((u >> 16) & 1u);          // RNE
    return (unsigned short)(u >> 16);
}
__device__ __forceinline__ float bf2f(unsigned short h) {
    return __uint_as_float(((unsigned int)h) << 16);
}
__device__ __forceinline__ float bflo(unsigned v) { return __uint_as_float(v << 16); }
__device__ __forceinline__ float bfhi(unsigned v) { return __uint_as_float(v & 0xffff0000u); }

// ---------------------------------------------------------------------------
// bf16 MFMA GEMM, 128x128 tile, 4 waves (64x64/wave), K staged 64 at a time.
// MODE 0: A = Af (fp32, Ktot=128), converted to bf16 during staging.
// MODE 1: A = concat-K [A0 | A1] (bf16, Ktot=256).  out may alias A0.
// BT: [128(N)][Ktot] bf16 pre-transposed.
// ---------------------------------------------------------------------------
#define BM  128
#define BKP 72   // 64 + 8 pad ushorts

template <int MODE>
__global__ __launch_bounds__(256) void gemm_mfma(
    const float* __restrict__ Af, const unsigned short* A0,
    const unsigned short* A1, const unsigned short* __restrict__ BT,
    const float* __restrict__ bias, unsigned short* out, int M)
{
    constexpr int Ktot = (MODE == 0) ? 128 : 256;
    __shared__ unsigned short As[BM][BKP];
    __shared__ unsigned short Bs[128][BKP];

    const int t    = threadIdx.x;
    const int wave = t >> 6, lane = t & 63;
    const int wr   = wave >> 1, wc = wave & 1;
    const int row0 = blockIdx.x * BM;

    f32x4 acc[4][4];
#pragma unroll
    for (int m = 0; m < 4; m++)
#pragma unroll
        for (int n = 0; n < 4; n++) acc[m][n] = (f32x4)0.f;

    for (int s = 0; s < (Ktot >> 6); s++) {
        const int kb = s * 64;
        __syncthreads();
        if (MODE == 0) {
#pragma unroll
            for (int it = 0; it < 4; it++) {
                const int idx = t + it * 256;
                const int r = idx >> 3, c8 = (idx & 7) * 8;
                uint4 o = make_uint4(0, 0, 0, 0);
                if (row0 + r < M) {
                    const float* p = &Af[(size_t)(row0 + r) * D_H + kb + c8];
                    const float4 v0 = *(const float4*)p;
                    const float4 v1 = *(const float4*)(p + 4);
                    o.x = (unsigned)f2bf(v0.x) | ((unsigned)f2bf(v0.y) << 16);
                    o.y = (unsigned)f2bf(v0.z) | ((unsigned)f2bf(v0.w) << 16);
                    o.z = (unsigned)f2bf(v1.x) | ((unsigned)f2bf(v1.y) << 16);
                    o.w = (unsigned)f2bf(v1.z) | ((unsigned)f2bf(v1.w) << 16);
                }
                *(uint4*)&As[r][c8] = o;
            }
        } else {
            const unsigned short* Asrc = (kb < 128) ? A0 : A1;
            const int ka = kb & 127;
#pragma unroll
            for (int it = 0; it < 4; it++) {
                const int idx = t + it * 256;
                const int r = idx >> 3, c8 = (idx & 7) * 8;
                uint4 v = make_uint4(0, 0, 0, 0);
                if (row0 + r < M)
                    v = *(const uint4*)&Asrc[(size_t)(row0 + r) * D_H + ka + c8];
                *(uint4*)&As[r][c8] = v;
            }
        }
#pragma unroll
        for (int it = 0; it < 4; it++) {
            const int idx = t + it * 256;
            const int n = idx >> 3, c8 = (idx & 7) * 8;
            *(uint4*)&Bs[n][c8] = *(const uint4*)&BT[(size_t)n * Ktot + kb + c8];
        }
        __syncthreads();

#pragma unroll
        for (int kk = 0; kk < 64; kk += 32) {
            const int koff = kk + (lane >> 4) * 8;
            bf16x8 af[4], bfr[4];
#pragma unroll
            for (int m = 0; m < 4; m++)
                af[m] = *(const bf16x8*)&As[wr * 64 + m * 16 + (lane & 15)][koff];
#pragma unroll
            for (int n = 0; n < 4; n++)
                bfr[n] = *(const bf16x8*)&Bs[wc * 64 + n * 16 + (lane & 15)][koff];
#pragma unroll
            for (int m = 0; m < 4; m++)
#pragma unroll
                for (int n = 0; n < 4; n++)
                    acc[m][n] = __builtin_amdgcn_mfma_f32_16x16x32_bf16(
                        af[m], bfr[n], acc[m][n], 0, 0, 0);
        }
    }

    float bv[4];
#pragma unroll
    for (int n = 0; n < 4; n++) bv[n] = bias[wc * 64 + n * 16 + (lane & 15)];

#pragma unroll
    for (int m = 0; m < 4; m++) {
#pragma unroll
        for (int j = 0; j < 4; j++) {
            const int row = row0 + wr * 64 + m * 16 + (lane >> 4) * 4 + j;
            if (row < M) {
#pragma unroll
                for (int n = 0; n < 4; n++) {
                    const int col = wc * 64 + n * 16 + (lane & 15);
                    out[(size_t)row * D_H + col] = f2bf(fmaxf(acc[m][n][j] + bv[n], 0.f));
                }
            }
        }
    }
}

// ---------------------------------------------------------------------------
// Weight prep: transposed bf16 weights
// ---------------------------------------------------------------------------
__global__ __launch_bounds__(256) void prep_bt(
    const float* __restrict__ W_in, const float* __restrict__ Wl,
    const float* __restrict__ Wr, unsigned short* __restrict__ BTin,
    unsigned short* __restrict__ BTl)
{
    const int i = blockIdx.x * blockDim.x + threadIdx.x;
    if (i < 128 * 128) {
        const int n = i >> 7, k = i & 127;
        BTin[n * 128 + k] = f2bf(W_in[k * 128 + n]);
    } else if (i < 128 * 128 + N_LAYERS * 128 * 256) {
        const int j = i - 128 * 128;
        const int l = j >> 15, r = j & 32767;
        const int n = r >> 8, k = r & 255;
        const float v = (k < 128) ? Wl[(size_t)l * 16384 + k * 128 + n]
                                  : Wr[(size_t)l * 16384 + (k - 128) * 128 + n];
        BTl[(size_t)l * 32768 + n * 256 + k] = f2bf(v);
    }
}

// ---------------------------------------------------------------------------
// CSR build via 256-bucket binning (bucket = dst>>9, 512 nodes each).
// ---------------------------------------------------------------------------
#define NBUK 256
#define EPB  8192
#define NBLK ((N_EDGES + EPB - 1) / EPB)     // 196

__global__ __launch_bounds__(256) void csr_count(
    const int* __restrict__ dst, int* __restrict__ cntMat)
{
    __shared__ int cnt[NBUK];
    cnt[threadIdx.x] = 0;
    __syncthreads();
    const int e0 = blockIdx.x * EPB;
    const int e1 = min(e0 + EPB, N_EDGES);
    for (int e = e0 + threadIdx.x; e < e1; e += 256)
        atomicAdd(&cnt[dst[e] >> 9], 1);
    __syncthreads();
    cntMat[threadIdx.x * NBLK + blockIdx.x] = cnt[threadIdx.x];
}

__global__ __launch_bounds__(256) void csr_scan_bucket(
    const int* __restrict__ cntMat, int* __restrict__ basMat, int* __restrict__ btot)
{
    __shared__ int s[256];
    const int b = blockIdx.x, t = threadIdx.x;
    const int v = (t < NBLK) ? cntMat[b * NBLK + t] : 0;
    s[t] = v; __syncthreads();
    for (int st = 1; st < 256; st <<= 1) {
        const int u = (t >= st) ? s[t - st] : 0;
        __syncthreads();
        s[t] += u;
        __syncthreads();
    }
    if (t < NBLK) basMat[b * NBLK + t] = s[t] - v;
    if (t == 255) btot[b] = s[255];
}

__global__ __launch_bounds__(256) void csr_scan_top(
    const int* __restrict__ btot, int* __restrict__ bbase)
{
    __shared__ int s[NBUK];
    const int t = threadIdx.x;
    const int v = btot[t];
    s[t] = v; __syncthreads();
    for (int st = 1; st < 256; st <<= 1) {
        const int u = (t >= st) ? s[t - st] : 0;
        __syncthreads();
        s[t] += u;
        __syncthreads();
    }
    bbase[t] = s[t] - v;
}

__global__ __launch_bounds__(256) void csr_scatter(
    const int* __restrict__ src, const int* __restrict__ dst,
    const int* __restrict__ basMat, const int* __restrict__ bbase,
    int2* __restrict__ binned)
{
    __shared__ int cur[NBUK];
    cur[threadIdx.x] = bbase[threadIdx.x] + basMat[threadIdx.x * NBLK + blockIdx.x];
    __syncthreads();
    const int e0 = blockIdx.x * EPB;
    const int e1 = min(e0 + EPB, N_EDGES);
    for (int e = e0 + threadIdx.x; e < e1; e += 256) {
        const int d = dst[e];
        const int pos = atomicAdd(&cur[d >> 9], 1);
        binned[pos] = make_int2(src[e], d);
    }
}

__global__ __launch_bounds__(256) void csr_build(
    const int2* __restrict__ binned, const int* __restrict__ bbase,
    const int* __restrict__ btot, int* __restrict__ rp, int* __restrict__ deg,
    float* __restrict__ inv, int* __restrict__ csr)
{
    __shared__ int hist[512];
    __shared__ int psc[256];
    __shared__ int cur[512];
    const int b = blockIdx.x, t = threadIdx.x;
    const int base = bbase[b];
    const int cntE = btot[b];
    const int n0 = b << 9;

    hist[t] = 0; hist[t + 256] = 0;
    __syncthreads();
    for (int i = t; i < cntE; i += 256)
        atomicAdd(&hist[binned[base + i].y - n0], 1);
    __syncthreads();

    const int h0 = hist[2 * t], h1 = hist[2 * t + 1];
    const int own = h0 + h1;
    psc[t] = own; __syncthreads();
    for (int st = 1; st < 256; st <<= 1) {
        const int u = (t >= st) ? psc[t - st] : 0;
        __syncthreads();
        psc[t] += u;
        __syncthreads();
    }
    const int pairExcl = psc[t] - own;
    cur[2 * t]     = pairExcl;
    cur[2 * t + 1] = pairExcl + h0;
    const int node0 = n0 + 2 * t, node1 = n0 + 2 * t + 1;
    if (node0 < N_NODES) {
        rp[node0] = base + pairExcl; deg[node0] = h0;
        inv[node0] = 1.f / fmaxf((float)h0, 1.f);
    }
    if (node1 < N_NODES) {
        rp[node1] = base + pairExcl + h0; deg[node1] = h1;
        inv[node1] = 1.f / fmaxf((float)h1, 1.f);
    }
    __syncthreads();
    for (int i = t; i < cntE; i += 256) {
        const int2 r = binned[base + i];
        const int pos = atomicAdd(&cur[r.y - n0], 1);
        csr[base + pos] = r.x;
    }
}

// ---------------------------------------------------------------------------
// Gather-mean v2: wave per node, 4x16-lane groups. Each lane owns 8 features
// (uint4, 16B); group g handles edges j = s0+g, s0+g+4, ... -> a wave reads
// 4 full 256B rows per load instruction. Cross-group reduce via shfl_xor.
// ---------------------------------------------------------------------------
__global__ __launch_bounds__(256) void gather_mean(
    const unsigned short* __restrict__ h, const int* __restrict__ csr,
    const int* __restrict__ rp, const int* __restrict__ deg,
    const float* __restrict__ inv, unsigned short* __restrict__ agg)
{
    const int wave   = (blockIdx.x * blockDim.x + threadIdx.x) >> 6;
    const int lane   = threadIdx.x & 63;
    const int grp    = lane >> 4;            // 0..3
    const int fl     = (lane & 15) * 8;      // feature base (8 bf16 = 16B)
    const int nwaves = (gridDim.x * blockDim.x) >> 6;

    for (int n = wave; n < N_NODES; n += nwaves) {
        const int s0 = rp[n];
        const int s1 = s0 + deg[n];
        float a[8];
#pragma unroll
        for (int k = 0; k < 8; k++) a[k] = 0.f;

        for (int j = s0 + grp; j < s1; j += 4) {
            const int s = csr[j];
            const uint4 v = *(const uint4*)&h[(size_t)s * D_H + fl];
            a[0] += bflo(v.x); a[1] += bfhi(v.x);
            a[2] += bflo(v.y); a[3] += bfhi(v.y);
            a[4] += bflo(v.z); a[5] += bfhi(v.z);
            a[6] += bflo(v.w); a[7] += bfhi(v.w);
        }
#pragma unroll
        for (int k = 0; k < 8; k++) a[k] += __shfl_xor(a[k], 16, 64);
#pragma unroll
        for (int k = 0; k < 8; k++) a[k] += __shfl_xor(a[k], 32, 64);

        if (grp == 0) {
            const float sc = inv[n];
            uint4 o;
            o.x = (unsigned)f2bf(a[0] * sc) | ((unsigned)f2bf(a[1] * sc) << 16);
            o.y = (unsigned)f2bf(a[2] * sc) | ((unsigned)f2bf(a[3] * sc) << 16);
            o.z = (unsigned)f2bf(a[4] * sc) | ((unsigned)f2bf(a[5] * sc) << 16);
            o.w = (unsigned)f2bf(a[6] * sc) | ((unsigned)f2bf(a[7] * sc) << 16);
            *(uint4*)&agg[(size_t)n * D_H + fl] = o;
        }
    }
}

// graph node counts via binary search on sorted batch_idx
__global__ __launch_bounds__(256) void graph_cnt_kernel(
    const int* __restrict__ batch, float* __restrict__ cnt)
{
    const int g = blockIdx.x * blockDim.x + threadIdx.x;
    if (g >= N_GRAPHS) return;
    auto lb = [&](int v) {
        int lo = 0, hi = N_NODES;
        while (lo < hi) { const int m = (lo + hi) >> 1; if (batch[m] < v) lo = m + 1; else hi = m; }
        return lo;
    };
    cnt[g] = (float)(lb(g + 1) - lb(g));
}

// ---------------------------------------------------------------------------
// Pooling on bf16 h: run-length accumulate (batch sorted)
// ---------------------------------------------------------------------------
#define NPB 512
__global__ __launch_bounds__(256) void pool_kernel(
    const unsigned short* __restrict__ h, const int* __restrict__ batch,
    float* __restrict__ sumb, float* __restrict__ maxb)
{
    const int f   = threadIdx.x & 127;
    const int sub = threadIdx.x >> 7;
    const int n0  = blockIdx.x * NPB;
    const int nEnd = min(n0 + NPB, N_NODES);
    float sum = 0.f, mx = 0.f;
    int g = -1;
    for (int n = n0 + sub; n < nEnd; n += 2) {
        const int gb = batch[n];
        if (gb != g) {
            if (g >= 0) {
                atomicAdd(&sumb[g * D_H + f], sum);
                atomicMax((int*)&maxb[g * D_H + f], __float_as_int(mx));
            }
            g = gb; sum = 0.f; mx = 0.f;
        }
        const float v = bf2f(h[(size_t)n * D_H + f]);
        sum += v; mx = fmaxf(mx, v);
    }
    if (g >= 0) {
        atomicAdd(&sumb[g * D_H + f], sum);
        atomicMax((int*)&maxb[g * D_H + f], __float_as_int(mx));
    }
}

// ---------------------------------------------------------------------------
// Head MLP (fp32)
// ---------------------------------------------------------------------------
__global__ __launch_bounds__(128) void mlp_kernel(
    const float* __restrict__ sumb, const float* __restrict__ maxb,
    const float* __restrict__ cnt,  const float* __restrict__ gf,
    const float* __restrict__ W1, const float* __restrict__ b1,
    const float* __restrict__ W2, const float* __restrict__ b2,
    float* __restrict__ out)
{
    __shared__ float z[2 * D_H + 32];
    __shared__ float z1[D_H];
    const int g = blockIdx.x, t = threadIdx.x;
    const float ic = 1.0f / fmaxf(cnt[g], 1.0f);
    z[t]        = sumb[g * D_H + t] * ic;
    z[D_H + t]  = maxb[g * D_H + t];
    if (t < 32) z[2 * D_H + t] = gf[g * 32 + t];
    __syncthreads();
    float a = b1[t];
    for (int k = 0; k < 2 * D_H + 32; k++) a += z[k] * W1[k * D_H + t];
    a = fmaxf(a, 0.f);
    z1[t] = a;
    __syncthreads();
    float o = b2[t];
    for (int k = 0; k < D_H; k++) o += z1[k] * W2[k * D_H + t];
    out[g * D_H + t] = fmaxf(o, 0.f);
}

// ---------------------------------------------------------------------------
extern "C" void kernel_launch(void* const* d_in, const int* in_sizes, int n_in,
                              void* d_out, int out_size, void* d_ws, size_t ws_size,
                              hipStream_t stream)
{
    const float* x     = (const float*)d_in[0];
    const int*   ei    = (const int*)d_in[1];
    const int*   batch = (const int*)d_in[2];
    const float* gf    = (const float*)d_in[3];
    const float* W_in  = (const float*)d_in[4];
    const float* b_in  = (const float*)d_in[5];
    const float* Wl    = (const float*)d_in[6];
    const float* bl    = (const float*)d_in[7];
    const float* Wr    = (const float*)d_in[8];
    const float* W1    = (const float*)d_in[9];
    const float* b1    = (const float*)d_in[10];
    const float* W2    = (const float*)d_in[11];
    const float* b2    = (const float*)d_in[12];
    float* out = (float*)d_out;

    const int* srcI = ei;
    const int* dstI = ei + N_EDGES;

    char* ws = (char*)d_ws;
    size_t off = 0;
    auto alloc = [&](size_t bytes) {
        char* p = ws + off;
        off += (bytes + 511) / 512 * 512;
        return p;
    };
    const size_t hB16 = (size_t)N_NODES * D_H * sizeof(unsigned short);
    unsigned short* bufA = (unsigned short*)alloc(hB16);
    unsigned short* bufB = (unsigned short*)alloc(hB16);
    unsigned short* BTin = (unsigned short*)alloc(128 * 128 * sizeof(unsigned short));
    unsigned short* BTl  = (unsigned short*)alloc((size_t)N_LAYERS * 128 * 256 * sizeof(unsigned short));
    int*   degI   = (int*)alloc(N_NODES * sizeof(int));
    float* inv    = (float*)alloc(N_NODES * sizeof(float));
    int*   rp     = (int*)alloc(N_NODES * sizeof(int));
    int*   csr    = (int*)alloc((size_t)N_EDGES * sizeof(int));
    int2*  binned = (int2*)alloc((size_t)N_EDGES * sizeof(int2));
    int*   cntMat = (int*)alloc((size_t)NBUK * NBLK * sizeof(int));
    int*   basMat = (int*)alloc((size_t)NBUK * NBLK * sizeof(int));
    int*   btot   = (int*)alloc(NBUK * sizeof(int));
    int*   bbase  = (int*)alloc(NBUK * sizeof(int));
    float* sumb   = (float*)alloc(N_GRAPHS * D_H * sizeof(float));
    float* maxb   = (float*)alloc(N_GRAPHS * D_H * sizeof(float));
    float* cnt    = (float*)alloc(N_GRAPHS * sizeof(float));

    hipMemsetAsync(sumb, 0, N_GRAPHS * D_H * sizeof(float), stream);
    hipMemsetAsync(maxb, 0, N_GRAPHS * D_H * sizeof(float), stream);

    graph_cnt_kernel<<<(N_GRAPHS + 255) / 256, 256, 0, stream>>>(batch, cnt);

    // CSR build (atomic-free, binned)
    csr_count<<<NBLK, 256, 0, stream>>>(dstI, cntMat);
    csr_scan_bucket<<<NBUK, 256, 0, stream>>>(cntMat, basMat, btot);
    csr_scan_top<<<1, 256, 0, stream>>>(btot, bbase);
    csr_scatter<<<NBLK, 256, 0, stream>>>(srcI, dstI, basMat, bbase, binned);
    csr_build<<<NBUK, 256, 0, stream>>>(binned, bbase, btot, rp, degI, inv, csr);

    prep_bt<<<(128 * 128 + N_LAYERS * 128 * 256 + 255) / 256, 256, 0, stream>>>(
        W_in, Wl, Wr, BTin, BTl);

    const int gblocks = (N_NODES + BM - 1) / BM;
    gemm_mfma<0><<<gblocks, 256, 0, stream>>>(x, nullptr, nullptr, BTin, b_in, bufA, N_NODES);

    unsigned short* h   = bufA;
    unsigned short* agg = bufB;
    for (int l = 0; l < N_LAYERS; l++) {
        gather_mean<<<2048, 256, 0, stream>>>(h, csr, rp, degI, inv, agg);
        gemm_mfma<1><<<gblocks, 256, 0, stream>>>(nullptr, agg, h, BTl + (size_t)l * 32768,
                                                  bl + (size_t)l * D_H, agg, N_NODES);
        unsigned short* tmp = h; h = agg; agg = tmp;
    }

    pool_kernel<<<(N_NODES + NPB - 1) / NPB, 256, 0, stream>>>(h, batch, sumb, maxb);
    mlp_kernel<<<N_GRAPHS, 128, 0, stream>>>(sumb, maxb, cnt, gf, W1, b1, W2, b2, out);
}

// Round 6
// 386.377 us; speedup vs baseline: 22.2700x; 1.2051x over previous
//
#include <hip/hip_runtime.h>

#define N_NODES  100000
#define N_EDGES  1600000
#define N_GRAPHS 512
#define D_H      128
#define N_LAYERS 3

typedef __attribute__((ext_vector_type(8))) short bf16x8;
typedef __attribute__((ext_vector_type(4))) float f32x4;

__device__ __forceinline__ unsigned short f2bf(float f) {
    unsigned int u = __float_as_uint(f);
    u += 0x7fffu + ((u >> 16) & 1u);          // RNE
    return (unsigned short)(u >> 16);
}
__device__ __forceinline__ float bf2f(unsigned short h) {
    return __uint_as_float(((unsigned int)h) << 16);
}
__device__ __forceinline__ float bflo(unsigned v) { return __uint_as_float(v << 16); }
__device__ __forceinline__ float bfhi(unsigned v) { return __uint_as_float(v & 0xffff0000u); }

// ---------------------------------------------------------------------------
// bf16 MFMA GEMM, 128x128 tile, 4 waves (64x64/wave), K staged 64 at a time.
// MODE 0: A = Af (fp32, Ktot=128), converted to bf16 during staging.
// MODE 1: A = concat-K [A0 | A1] (bf16, Ktot=256).  out may alias A0.
// BT: [128(N)][Ktot] bf16 pre-transposed.
// ---------------------------------------------------------------------------
#define BM  128
#define BKP 72   // 64 + 8 pad ushorts

template <int MODE>
__global__ __launch_bounds__(256) void gemm_mfma(
    const float* __restrict__ Af, const unsigned short* A0,
    const unsigned short* A1, const unsigned short* __restrict__ BT,
    const float* __restrict__ bias, unsigned short* out, int M)
{
    constexpr int Ktot = (MODE == 0) ? 128 : 256;
    __shared__ unsigned short As[BM][BKP];
    __shared__ unsigned short Bs[128][BKP];

    const int t    = threadIdx.x;
    const int wave = t >> 6, lane = t & 63;
    const int wr   = wave >> 1, wc = wave & 1;
    const int row0 = blockIdx.x * BM;

    f32x4 acc[4][4];
#pragma unroll
    for (int m = 0; m < 4; m++)
#pragma unroll
        for (int n = 0; n < 4; n++) acc[m][n] = (f32x4)0.f;

    for (int s = 0; s < (Ktot >> 6); s++) {
        const int kb = s * 64;
        __syncthreads();
        if (MODE == 0) {
#pragma unroll
            for (int it = 0; it < 4; it++) {
                const int idx = t + it * 256;
                const int r = idx >> 3, c8 = (idx & 7) * 8;
                uint4 o = make_uint4(0, 0, 0, 0);
                if (row0 + r < M) {
                    const float* p = &Af[(size_t)(row0 + r) * D_H + kb + c8];
                    const float4 v0 = *(const float4*)p;
                    const float4 v1 = *(const float4*)(p + 4);
                    o.x = (unsigned)f2bf(v0.x) | ((unsigned)f2bf(v0.y) << 16);
                    o.y = (unsigned)f2bf(v0.z) | ((unsigned)f2bf(v0.w) << 16);
                    o.z = (unsigned)f2bf(v1.x) | ((unsigned)f2bf(v1.y) << 16);
                    o.w = (unsigned)f2bf(v1.z) | ((unsigned)f2bf(v1.w) << 16);
                }
                *(uint4*)&As[r][c8] = o;
            }
        } else {
            const unsigned short* Asrc = (kb < 128) ? A0 : A1;
            const int ka = kb & 127;
#pragma unroll
            for (int it = 0; it < 4; it++) {
                const int idx = t + it * 256;
                const int r = idx >> 3, c8 = (idx & 7) * 8;
                uint4 v = make_uint4(0, 0, 0, 0);
                if (row0 + r < M)
                    v = *(const uint4*)&Asrc[(size_t)(row0 + r) * D_H + ka + c8];
                *(uint4*)&As[r][c8] = v;
            }
        }
#pragma unroll
        for (int it = 0; it < 4; it++) {
            const int idx = t + it * 256;
            const int n = idx >> 3, c8 = (idx & 7) * 8;
            *(uint4*)&Bs[n][c8] = *(const uint4*)&BT[(size_t)n * Ktot + kb + c8];
        }
        __syncthreads();

#pragma unroll
        for (int kk = 0; kk < 64; kk += 32) {
            const int koff = kk + (lane >> 4) * 8;
            bf16x8 af[4], bfr[4];
#pragma unroll
            for (int m = 0; m < 4; m++)
                af[m] = *(const bf16x8*)&As[wr * 64 + m * 16 + (lane & 15)][koff];
#pragma unroll
            for (int n = 0; n < 4; n++)
                bfr[n] = *(const bf16x8*)&Bs[wc * 64 + n * 16 + (lane & 15)][koff];
#pragma unroll
            for (int m = 0; m < 4; m++)
#pragma unroll
                for (int n = 0; n < 4; n++)
                    acc[m][n] = __builtin_amdgcn_mfma_f32_16x16x32_bf16(
                        af[m], bfr[n], acc[m][n], 0, 0, 0);
        }
    }

    float bv[4];
#pragma unroll
    for (int n = 0; n < 4; n++) bv[n] = bias[wc * 64 + n * 16 + (lane & 15)];

#pragma unroll
    for (int m = 0; m < 4; m++) {
#pragma unroll
        for (int j = 0; j < 4; j++) {
            const int row = row0 + wr * 64 + m * 16 + (lane >> 4) * 4 + j;
            if (row < M) {
#pragma unroll
                for (int n = 0; n < 4; n++) {
                    const int col = wc * 64 + n * 16 + (lane & 15);
                    out[(size_t)row * D_H + col] = f2bf(fmaxf(acc[m][n][j] + bv[n], 0.f));
                }
            }
        }
    }
}

// ---------------------------------------------------------------------------
// Weight prep: transposed bf16 weights
// ---------------------------------------------------------------------------
__global__ __launch_bounds__(256) void prep_bt(
    const float* __restrict__ W_in, const float* __restrict__ Wl,
    const float* __restrict__ Wr, unsigned short* __restrict__ BTin,
    unsigned short* __restrict__ BTl)
{
    const int i = blockIdx.x * blockDim.x + threadIdx.x;
    if (i < 128 * 128) {
        const int n = i >> 7, k = i & 127;
        BTin[n * 128 + k] = f2bf(W_in[k * 128 + n]);
    } else if (i < 128 * 128 + N_LAYERS * 128 * 256) {
        const int j = i - 128 * 128;
        const int l = j >> 15, r = j & 32767;
        const int n = r >> 8, k = r & 255;
        const float v = (k < 128) ? Wl[(size_t)l * 16384 + k * 128 + n]
                                  : Wr[(size_t)l * 16384 + (k - 128) * 128 + n];
        BTl[(size_t)l * 32768 + n * 256 + k] = f2bf(v);
    }
}

// ---------------------------------------------------------------------------
// CSR build via 256-bucket binning (bucket = dst>>9, 512 nodes each).
// ---------------------------------------------------------------------------
#define NBUK 256
#define EPB  8192
#define NBLK ((N_EDGES + EPB - 1) / EPB)     // 196

__global__ __launch_bounds__(256) void csr_count(
    const int* __restrict__ dst, int* __restrict__ cntMat)
{
    __shared__ int cnt[NBUK];
    cnt[threadIdx.x] = 0;
    __syncthreads();
    const int e0 = blockIdx.x * EPB;
    const int e1 = min(e0 + EPB, N_EDGES);
    for (int e = e0 + threadIdx.x; e < e1; e += 256)
        atomicAdd(&cnt[dst[e] >> 9], 1);
    __syncthreads();
    cntMat[threadIdx.x * NBLK + blockIdx.x] = cnt[threadIdx.x];
}

__global__ __launch_bounds__(256) void csr_scan_bucket(
    const int* __restrict__ cntMat, int* __restrict__ basMat, int* __restrict__ btot)
{
    __shared__ int s[256];
    const int b = blockIdx.x, t = threadIdx.x;
    const int v = (t < NBLK) ? cntMat[b * NBLK + t] : 0;
    s[t] = v; __syncthreads();
    for (int st = 1; st < 256; st <<= 1) {
        const int u = (t >= st) ? s[t - st] : 0;
        __syncthreads();
        s[t] += u;
        __syncthreads();
    }
    if (t < NBLK) basMat[b * NBLK + t] = s[t] - v;
    if (t == 255) btot[b] = s[255];
}

__global__ __launch_bounds__(256) void csr_scan_top(
    const int* __restrict__ btot, int* __restrict__ bbase)
{
    __shared__ int s[NBUK];
    const int t = threadIdx.x;
    const int v = btot[t];
    s[t] = v; __syncthreads();
    for (int st = 1; st < 256; st <<= 1) {
        const int u = (t >= st) ? s[t - st] : 0;
        __syncthreads();
        s[t] += u;
        __syncthreads();
    }
    bbase[t] = s[t] - v;
}

__global__ __launch_bounds__(256) void csr_scatter(
    const int* __restrict__ src, const int* __restrict__ dst,
    const int* __restrict__ basMat, const int* __restrict__ bbase,
    int2* __restrict__ binned)
{
    __shared__ int cur[NBUK];
    cur[threadIdx.x] = bbase[threadIdx.x] + basMat[threadIdx.x * NBLK + blockIdx.x];
    __syncthreads();
    const int e0 = blockIdx.x * EPB;
    const int e1 = min(e0 + EPB, N_EDGES);
    for (int e = e0 + threadIdx.x; e < e1; e += 256) {
        const int d = dst[e];
        const int pos = atomicAdd(&cur[d >> 9], 1);
        binned[pos] = make_int2(src[e], d);
    }
}

__global__ __launch_bounds__(256) void csr_build(
    const int2* __restrict__ binned, const int* __restrict__ bbase,
    const int* __restrict__ btot, int* __restrict__ rp, int* __restrict__ deg,
    float* __restrict__ inv, int* __restrict__ csr)
{
    __shared__ int hist[512];
    __shared__ int psc[256];
    __shared__ int cur[512];
    const int b = blockIdx.x, t = threadIdx.x;
    const int base = bbase[b];
    const int cntE = btot[b];
    const int n0 = b << 9;

    hist[t] = 0; hist[t + 256] = 0;
    __syncthreads();
    for (int i = t; i < cntE; i += 256)
        atomicAdd(&hist[binned[base + i].y - n0], 1);
    __syncthreads();

    const int h0 = hist[2 * t], h1 = hist[2 * t + 1];
    const int own = h0 + h1;
    psc[t] = own; __syncthreads();
    for (int st = 1; st < 256; st <<= 1) {
        const int u = (t >= st) ? psc[t - st] : 0;
        __syncthreads();
        psc[t] += u;
        __syncthreads();
    }
    const int pairExcl = psc[t] - own;
    cur[2 * t]     = pairExcl;
    cur[2 * t + 1] = pairExcl + h0;
    const int node0 = n0 + 2 * t, node1 = n0 + 2 * t + 1;
    if (node0 < N_NODES) {
        rp[node0] = base + pairExcl; deg[node0] = h0;
        inv[node0] = 1.f / fmaxf((float)h0, 1.f);
    }
    if (node1 < N_NODES) {
        rp[node1] = base + pairExcl + h0; deg[node1] = h1;
        inv[node1] = 1.f / fmaxf((float)h1, 1.f);
    }
    __syncthreads();
    for (int i = t; i < cntE; i += 256) {
        const int2 r = binned[base + i];
        const int pos = atomicAdd(&cur[r.y - n0], 1);
        csr[base + pos] = r.x;
    }
}

// ---------------------------------------------------------------------------
// Gather-mean v2: wave per node, 4x16-lane groups, uint4 per lane.
// ---------------------------------------------------------------------------
__global__ __launch_bounds__(256) void gather_mean(
    const unsigned short* __restrict__ h, const int* __restrict__ csr,
    const int* __restrict__ rp, const int* __restrict__ deg,
    const float* __restrict__ inv, unsigned short* __restrict__ agg)
{
    const int wave   = (blockIdx.x * blockDim.x + threadIdx.x) >> 6;
    const int lane   = threadIdx.x & 63;
    const int grp    = lane >> 4;            // 0..3
    const int fl     = (lane & 15) * 8;      // feature base (8 bf16 = 16B)
    const int nwaves = (gridDim.x * blockDim.x) >> 6;

    for (int n = wave; n < N_NODES; n += nwaves) {
        const int s0 = rp[n];
        const int s1 = s0 + deg[n];
        float a[8];
#pragma unroll
        for (int k = 0; k < 8; k++) a[k] = 0.f;

        for (int j = s0 + grp; j < s1; j += 4) {
            const int s = csr[j];
            const uint4 v = *(const uint4*)&h[(size_t)s * D_H + fl];
            a[0] += bflo(v.x); a[1] += bfhi(v.x);
            a[2] += bflo(v.y); a[3] += bfhi(v.y);
            a[4] += bflo(v.z); a[5] += bfhi(v.z);
            a[6] += bflo(v.w); a[7] += bfhi(v.w);
        }
#pragma unroll
        for (int k = 0; k < 8; k++) a[k] += __shfl_xor(a[k], 16, 64);
#pragma unroll
        for (int k = 0; k < 8; k++) a[k] += __shfl_xor(a[k], 32, 64);

        if (grp == 0) {
            const float sc = inv[n];
            uint4 o;
            o.x = (unsigned)f2bf(a[0] * sc) | ((unsigned)f2bf(a[1] * sc) << 16);
            o.y = (unsigned)f2bf(a[2] * sc) | ((unsigned)f2bf(a[3] * sc) << 16);
            o.z = (unsigned)f2bf(a[4] * sc) | ((unsigned)f2bf(a[5] * sc) << 16);
            o.w = (unsigned)f2bf(a[6] * sc) | ((unsigned)f2bf(a[7] * sc) << 16);
            *(uint4*)&agg[(size_t)n * D_H + fl] = o;
        }
    }
}

// ---------------------------------------------------------------------------
// Pooling v2: one block per graph (batch sorted). 64 threads cover a 256B row
// (uint = 2 features), 4 waves process 4 rows concurrently; LDS reduce; write
// mean (/=count) and max directly. No atomics, no memsets, no cnt kernel.
// ---------------------------------------------------------------------------
__global__ __launch_bounds__(256) void pool_graph(
    const unsigned short* __restrict__ h, const int* __restrict__ batch,
    float* __restrict__ meanb, float* __restrict__ maxb)
{
    __shared__ int bounds[2];
    __shared__ float2 ssum[256];
    __shared__ float2 smax[256];
    const int g = blockIdx.x, t = threadIdx.x;
    if (t < 2) {
        const int v = g + t;
        int lo = 0, hi = N_NODES;
        while (lo < hi) { const int m = (lo + hi) >> 1; if (batch[m] < v) lo = m + 1; else hi = m; }
        bounds[t] = lo;
    }
    __syncthreads();
    const int n0 = bounds[0], n1 = bounds[1];
    const int f2 = t & 63;     // uint index: features 2*f2, 2*f2+1
    const int sub = t >> 6;    // 0..3 (wave id)

    float sx = 0.f, sy = 0.f, mx = 0.f, my = 0.f;   // h >= 0 post-relu
    for (int n = n0 + sub; n < n1; n += 4) {
        const unsigned v = *(const unsigned*)&h[(size_t)n * D_H + f2 * 2];
        const float x = bflo(v), y = bfhi(v);
        sx += x; sy += y;
        mx = fmaxf(mx, x); my = fmaxf(my, y);
    }
    ssum[t] = make_float2(sx, sy);
    smax[t] = make_float2(mx, my);
    __syncthreads();
    if (sub == 0) {
        const float2 s0 = ssum[t], s1 = ssum[t + 64], s2 = ssum[t + 128], s3 = ssum[t + 192];
        const float2 m0 = smax[t], m1 = smax[t + 64], m2 = smax[t + 128], m3 = smax[t + 192];
        const float ic = 1.f / fmaxf((float)(n1 - n0), 1.f);
        meanb[g * D_H + f2 * 2]     = (s0.x + s1.x + s2.x + s3.x) * ic;
        meanb[g * D_H + f2 * 2 + 1] = (s0.y + s1.y + s2.y + s3.y) * ic;
        maxb[g * D_H + f2 * 2]      = fmaxf(fmaxf(m0.x, m1.x), fmaxf(m2.x, m3.x));
        maxb[g * D_H + f2 * 2 + 1]  = fmaxf(fmaxf(m0.y, m1.y), fmaxf(m2.y, m3.y));
    }
}

// ---------------------------------------------------------------------------
// Head MLP (fp32): z = [mean, max, gf]
// ---------------------------------------------------------------------------
__global__ __launch_bounds__(128) void mlp_kernel(
    const float* __restrict__ meanb, const float* __restrict__ maxb,
    const float* __restrict__ gf,
    const float* __restrict__ W1, const float* __restrict__ b1,
    const float* __restrict__ W2, const float* __restrict__ b2,
    float* __restrict__ out)
{
    __shared__ float z[2 * D_H + 32];
    __shared__ float z1[D_H];
    const int g = blockIdx.x, t = threadIdx.x;
    z[t]       = meanb[g * D_H + t];
    z[D_H + t] = maxb[g * D_H + t];
    if (t < 32) z[2 * D_H + t] = gf[g * 32 + t];
    __syncthreads();
    float a = b1[t];
    for (int k = 0; k < 2 * D_H + 32; k++) a += z[k] * W1[k * D_H + t];
    a = fmaxf(a, 0.f);
    z1[t] = a;
    __syncthreads();
    float o = b2[t];
    for (int k = 0; k < D_H; k++) o += z1[k] * W2[k * D_H + t];
    out[g * D_H + t] = fmaxf(o, 0.f);
}

// ---------------------------------------------------------------------------
extern "C" void kernel_launch(void* const* d_in, const int* in_sizes, int n_in,
                              void* d_out, int out_size, void* d_ws, size_t ws_size,
                              hipStream_t stream)
{
    const float* x     = (const float*)d_in[0];
    const int*   ei    = (const int*)d_in[1];
    const int*   batch = (const int*)d_in[2];
    const float* gf    = (const float*)d_in[3];
    const float* W_in  = (const float*)d_in[4];
    const float* b_in  = (const float*)d_in[5];
    const float* Wl    = (const float*)d_in[6];
    const float* bl    = (const float*)d_in[7];
    const float* Wr    = (const float*)d_in[8];
    const float* W1    = (const float*)d_in[9];
    const float* b1    = (const float*)d_in[10];
    const float* W2    = (const float*)d_in[11];
    const float* b2    = (const float*)d_in[12];
    float* out = (float*)d_out;

    const int* srcI = ei;
    const int* dstI = ei + N_EDGES;

    char* ws = (char*)d_ws;
    size_t off = 0;
    auto alloc = [&](size_t bytes) {
        char* p = ws + off;
        off += (bytes + 511) / 512 * 512;
        return p;
    };
    const size_t hB16 = (size_t)N_NODES * D_H * sizeof(unsigned short);
    unsigned short* bufA = (unsigned short*)alloc(hB16);
    unsigned short* bufB = (unsigned short*)alloc(hB16);
    unsigned short* BTin = (unsigned short*)alloc(128 * 128 * sizeof(unsigned short));
    unsigned short* BTl  = (unsigned short*)alloc((size_t)N_LAYERS * 128 * 256 * sizeof(unsigned short));
    int*   degI   = (int*)alloc(N_NODES * sizeof(int));
    float* inv    = (float*)alloc(N_NODES * sizeof(float));
    int*   rp     = (int*)alloc(N_NODES * sizeof(int));
    int*   csr    = (int*)alloc((size_t)N_EDGES * sizeof(int));
    int2*  binned = (int2*)alloc((size_t)N_EDGES * sizeof(int2));
    int*   cntMat = (int*)alloc((size_t)NBUK * NBLK * sizeof(int));
    int*   basMat = (int*)alloc((size_t)NBUK * NBLK * sizeof(int));
    int*   btot   = (int*)alloc(NBUK * sizeof(int));
    int*   bbase  = (int*)alloc(NBUK * sizeof(int));
    float* meanb  = (float*)alloc(N_GRAPHS * D_H * sizeof(float));
    float* maxb   = (float*)alloc(N_GRAPHS * D_H * sizeof(float));

    // CSR build (atomic-free, binned)
    csr_count<<<NBLK, 256, 0, stream>>>(dstI, cntMat);
    csr_scan_bucket<<<NBUK, 256, 0, stream>>>(cntMat, basMat, btot);
    csr_scan_top<<<1, 256, 0, stream>>>(btot, bbase);
    csr_scatter<<<NBLK, 256, 0, stream>>>(srcI, dstI, basMat, bbase, binned);
    csr_build<<<NBUK, 256, 0, stream>>>(binned, bbase, btot, rp, degI, inv, csr);

    prep_bt<<<(128 * 128 + N_LAYERS * 128 * 256 + 255) / 256, 256, 0, stream>>>(
        W_in, Wl, Wr, BTin, BTl);

    const int gblocks = (N_NODES + BM - 1) / BM;
    gemm_mfma<0><<<gblocks, 256, 0, stream>>>(x, nullptr, nullptr, BTin, b_in, bufA, N_NODES);

    unsigned short* h   = bufA;
    unsigned short* agg = bufB;
    for (int l = 0; l < N_LAYERS; l++) {
        gather_mean<<<2048, 256, 0, stream>>>(h, csr, rp, degI, inv, agg);
        gemm_mfma<1><<<gblocks, 256, 0, stream>>>(nullptr, agg, h, BTl + (size_t)l * 32768,
                                                  bl + (size_t)l * D_H, agg, N_NODES);
        unsigned short* tmp = h; h = agg; agg = tmp;
    }

    pool_graph<<<N_GRAPHS, 256, 0, stream>>>(h, batch, meanb, maxb);
    mlp_kernel<<<N_GRAPHS, 128, 0, stream>>>(meanb, maxb, gf, W1, b1, W2, b2, out);
}